// Round 1
// baseline (1064.863 us; speedup 1.0000x reference)
//
#include <hip/hip_runtime.h>

#define NCH 128

// ---------------- degree / CSR build ----------------

__global__ __launch_bounds__(256) void k_deg_init(int* __restrict__ deg, int n) {
  int i = blockIdx.x * 256 + threadIdx.x;
  if (i < n) deg[i] = 1;  // self-loop
}

__global__ __launch_bounds__(256) void k_deg_count(const int* __restrict__ dst,
                                                   int* __restrict__ deg, int E) {
  int stride = gridDim.x * 256;
  for (int e = blockIdx.x * 256 + threadIdx.x; e < E; e += stride)
    atomicAdd(&deg[dst[e]], 1);
}

__global__ __launch_bounds__(256) void k_dis(const int* __restrict__ deg,
                                             float* __restrict__ dis, int n) {
  int i = blockIdx.x * 256 + threadIdx.x;
  if (i < n) dis[i] = rsqrtf((float)deg[i]);
}

__global__ __launch_bounds__(1024) void k_scan_block(const int* __restrict__ deg,
                                                     int* __restrict__ rptmp,
                                                     int* __restrict__ bsum, int n) {
  __shared__ int s[1024];
  int tid = threadIdx.x;
  int gid = blockIdx.x * 1024 + tid;
  int v = (gid < n) ? (deg[gid] - 1) : 0;  // in-degree excluding self-loop
  s[tid] = v;
  __syncthreads();
  for (int off = 1; off < 1024; off <<= 1) {
    int t = (tid >= off) ? s[tid - off] : 0;
    __syncthreads();
    s[tid] += t;
    __syncthreads();
  }
  if (gid < n) rptmp[gid] = s[tid] - v;  // exclusive
  if (tid == 1023) bsum[blockIdx.x] = s[1023];
}

__global__ void k_scan_total(const int* __restrict__ bsum, int* __restrict__ boff, int nb) {
  if (threadIdx.x == 0 && blockIdx.x == 0) {
    int acc = 0;
    for (int b = 0; b < nb; ++b) { boff[b] = acc; acc += bsum[b]; }
  }
}

__global__ __launch_bounds__(256) void k_scan_finish(const int* __restrict__ rptmp,
                                                     const int* __restrict__ boff,
                                                     int* __restrict__ rowptr,
                                                     int* __restrict__ fillpos, int n, int E) {
  int i = blockIdx.x * 256 + threadIdx.x;
  if (i < n) {
    int v = rptmp[i] + boff[i >> 10];
    rowptr[i] = v;
    fillpos[i] = v;
  }
  if (i == 0) rowptr[n] = E;
}

__global__ __launch_bounds__(256) void k_fill(const int* __restrict__ src,
                                              const int* __restrict__ dst,
                                              int* __restrict__ fillpos,
                                              int* __restrict__ col, int E) {
  int stride = gridDim.x * 256;
  for (int e = blockIdx.x * 256 + threadIdx.x; e < E; e += stride) {
    int p = atomicAdd(&fillpos[dst[e]], 1);
    col[p] = src[e];
  }
}

// ---------------- GEMM: T[n][c] = dis[n] * sum_k X[n][k]*W[k][c] ----------------
// tile 64 rows x 64 cols, 256 threads, thread = 4 rows x 4 cols

template <int COUT>
__global__ __launch_bounds__(256) void k_gemm_scale(const float* __restrict__ X,
                                                    const float* __restrict__ W,
                                                    const float* __restrict__ dis,
                                                    float* __restrict__ T, int nrows) {
  __shared__ float xs[64][132];   // row-major x tile, padded (132*4 % 16 == 0)
  __shared__ float ws[128][68];   // k x col tile, padded
  const int tid = threadIdx.x;
  const int row0 = blockIdx.x * 64;
  const int c0 = blockIdx.y * 64;

#pragma unroll
  for (int i = 0; i < 8; ++i) {
    int idx = tid + i * 256;       // 0..2047 over 64 rows x 32 k-quads
    int r = idx >> 5, kk = idx & 31;
    int row = row0 + r;
    float4 v = make_float4(0.f, 0.f, 0.f, 0.f);
    if (row < nrows) v = *reinterpret_cast<const float4*>(X + (size_t)row * NCH + kk * 4);
    *reinterpret_cast<float4*>(&xs[r][kk * 4]) = v;
  }
#pragma unroll
  for (int i = 0; i < 8; ++i) {
    int idx = tid + i * 256;       // 0..2047 over 128 k x 16 col-quads
    int k = idx >> 4, q = idx & 15;
    float4 v = *reinterpret_cast<const float4*>(W + (size_t)k * COUT + c0 + q * 4);
    *reinterpret_cast<float4*>(&ws[k][q * 4]) = v;
  }
  __syncthreads();

  const int tc = tid & 15, tr = tid >> 4;
  float4 acc0 = make_float4(0.f, 0.f, 0.f, 0.f);
  float4 acc1 = acc0, acc2 = acc0, acc3 = acc0;

#define FMA4(ACC, S, B)                                                                \
  ACC.x = fmaf(S, B.x, ACC.x); ACC.y = fmaf(S, B.y, ACC.y);                            \
  ACC.z = fmaf(S, B.z, ACC.z); ACC.w = fmaf(S, B.w, ACC.w)

#pragma unroll 8
  for (int k = 0; k < 128; k += 4) {
    float4 A0 = *reinterpret_cast<const float4*>(&xs[4 * tr + 0][k]);
    float4 A1 = *reinterpret_cast<const float4*>(&xs[4 * tr + 1][k]);
    float4 A2 = *reinterpret_cast<const float4*>(&xs[4 * tr + 2][k]);
    float4 A3 = *reinterpret_cast<const float4*>(&xs[4 * tr + 3][k]);
    float4 B0 = *reinterpret_cast<const float4*>(&ws[k + 0][4 * tc]);
    float4 B1 = *reinterpret_cast<const float4*>(&ws[k + 1][4 * tc]);
    float4 B2 = *reinterpret_cast<const float4*>(&ws[k + 2][4 * tc]);
    float4 B3 = *reinterpret_cast<const float4*>(&ws[k + 3][4 * tc]);
    FMA4(acc0, A0.x, B0); FMA4(acc0, A0.y, B1); FMA4(acc0, A0.z, B2); FMA4(acc0, A0.w, B3);
    FMA4(acc1, A1.x, B0); FMA4(acc1, A1.y, B1); FMA4(acc1, A1.z, B2); FMA4(acc1, A1.w, B3);
    FMA4(acc2, A2.x, B0); FMA4(acc2, A2.y, B1); FMA4(acc2, A2.z, B2); FMA4(acc2, A2.w, B3);
    FMA4(acc3, A3.x, B0); FMA4(acc3, A3.y, B1); FMA4(acc3, A3.z, B2); FMA4(acc3, A3.w, B3);
  }
#undef FMA4

  float4 accs[4] = {acc0, acc1, acc2, acc3};
#pragma unroll
  for (int i = 0; i < 4; ++i) {
    int row = row0 + 4 * tr + i;
    if (row < nrows) {
      float d = dis[row];
      float4 o;
      o.x = accs[i].x * d; o.y = accs[i].y * d; o.z = accs[i].z * d; o.w = accs[i].w * d;
      *reinterpret_cast<float4*>(T + (size_t)row * COUT + c0 + 4 * tc) = o;
    }
  }
}

// ---------------- pull aggregation: OUT[i] = dis[i]*(T'[i] + sum_{e in(i)} T'[src_e]) + b ----------------

template <int C>
__global__ __launch_bounds__(256) void k_aggregate(const float* __restrict__ T,
                                                   const int* __restrict__ rowptr,
                                                   const int* __restrict__ col,
                                                   const float* __restrict__ dis,
                                                   const float* __restrict__ bias,
                                                   float* __restrict__ OUT, int n) {
  const int lane = threadIdx.x & 63;
  const int node = blockIdx.x * 4 + (threadIdx.x >> 6);
  if (node >= n) return;
  const int beg = rowptr[node], end = rowptr[node + 1];

  if constexpr (C == 128) {
    float2 acc = *reinterpret_cast<const float2*>(T + (size_t)node * 128 + lane * 2);
    for (int e = beg; e < end;) {
      int cnt = end - e;
      if (cnt > 64) cnt = 64;
      int sl = (e + lane < end) ? col[e + lane] : 0;
      for (int j = 0; j < cnt; ++j) {
        int s = __shfl(sl, j);
        float2 v = *reinterpret_cast<const float2*>(T + (size_t)s * 128 + lane * 2);
        acc.x += v.x;
        acc.y += v.y;
      }
      e += cnt;
    }
    float d = dis[node];
    float2 o;
    o.x = fmaf(acc.x, d, bias[lane * 2]);
    o.y = fmaf(acc.y, d, bias[lane * 2 + 1]);
    *reinterpret_cast<float2*>(OUT + (size_t)node * 128 + lane * 2) = o;
  } else {
    float acc = T[(size_t)node * 64 + lane];
    for (int e = beg; e < end;) {
      int cnt = end - e;
      if (cnt > 64) cnt = 64;
      int sl = (e + lane < end) ? col[e + lane] : 0;
      for (int j = 0; j < cnt; ++j) {
        int s = __shfl(sl, j);
        acc += T[(size_t)s * 64 + lane];
      }
      e += cnt;
    }
    float d = dis[node];
    OUT[(size_t)node * 64 + lane] = fmaf(acc, d, bias[lane]);
  }
}

// ---------------- BatchNorm (training-mode batch stats) + ReLU ----------------

__global__ __launch_bounds__(256) void k_bn_partial(const float* __restrict__ H,
                                                    float* __restrict__ part, int nrows) {
  const int c = threadIdx.x & 127;
  const int half = threadIdx.x >> 7;
  float s = 0.f, s2 = 0.f;
  for (int r = blockIdx.x * 2 + half; r < nrows; r += gridDim.x * 2) {
    float v = H[(size_t)r * 128 + c];
    s += v;
    s2 += v * v;
  }
  __shared__ float ls[256], ls2[256];
  ls[threadIdx.x] = s;
  ls2[threadIdx.x] = s2;
  __syncthreads();
  if (half == 0) {
    part[(size_t)blockIdx.x * 256 + c] = ls[c] + ls[c + 128];
    part[(size_t)blockIdx.x * 256 + 128 + c] = ls2[c] + ls2[c + 128];
  }
}

__global__ __launch_bounds__(128) void k_bn_final(const float* __restrict__ part,
                                                  const float* __restrict__ g,
                                                  const float* __restrict__ bt,
                                                  float* __restrict__ ss, int G, int nrows) {
  const int c = threadIdx.x;  // 128
  float S = 0.f, S2 = 0.f;
  for (int b = 0; b < G; ++b) {
    S += part[(size_t)b * 256 + c];
    S2 += part[(size_t)b * 256 + 128 + c];
  }
  float inv_n = 1.f / (float)nrows;
  float mean = S * inv_n;
  float var = S2 * inv_n - mean * mean;
  float sc = g[c] * rsqrtf(var + 1e-5f);
  ss[c] = sc;
  ss[128 + c] = bt[c] - mean * sc;
}

__global__ __launch_bounds__(256) void k_bn_apply(float* __restrict__ H,
                                                  const float* __restrict__ ss, size_t n4) {
  size_t stride = (size_t)gridDim.x * 256;
  float4* H4 = reinterpret_cast<float4*>(H);
  for (size_t i = (size_t)blockIdx.x * 256 + threadIdx.x; i < n4; i += stride) {
    float4 v = H4[i];
    int c = (int)((i & 31) * 4);  // 128 floats per row = 32 float4
    float4 sc = *reinterpret_cast<const float4*>(&ss[c]);
    float4 sh = *reinterpret_cast<const float4*>(&ss[128 + c]);
    v.x = fmaxf(fmaf(v.x, sc.x, sh.x), 0.f);
    v.y = fmaxf(fmaf(v.y, sc.y, sh.y), 0.f);
    v.z = fmaxf(fmaf(v.z, sc.z, sh.z), 0.f);
    v.w = fmaxf(fmaf(v.w, sc.w, sh.w), 0.f);
    H4[i] = v;
  }
}

// ---------------- driver ----------------

extern "C" void kernel_launch(void* const* d_in, const int* in_sizes, int n_in,
                              void* d_out, int out_size, void* d_ws, size_t ws_size,
                              hipStream_t stream) {
  const float* x  = (const float*)d_in[0];
  const int* ei   = (const int*)d_in[1];
  const float* W1 = (const float*)d_in[2];
  const float* b1 = (const float*)d_in[3];
  const float* g1 = (const float*)d_in[4];
  const float* bt1= (const float*)d_in[5];
  const float* W2 = (const float*)d_in[6];
  const float* b2 = (const float*)d_in[7];
  const float* g2 = (const float*)d_in[8];
  const float* bt2= (const float*)d_in[9];
  const float* W3 = (const float*)d_in[10];
  const float* b3 = (const float*)d_in[11];

  const int N = in_sizes[0] / NCH;
  const int E = in_sizes[1] / 2;
  const int* src = ei;
  const int* dst = ei + E;

  char* p = (char*)d_ws;
  auto take = [&](size_t bytes) -> char* {
    char* r = p;
    p += (bytes + 255) & ~(size_t)255;
    return r;
  };
  float* bufT   = (float*)take((size_t)N * 128 * 4);
  float* bufH   = (float*)take((size_t)N * 128 * 4);
  int* deg      = (int*)take((size_t)N * 4);
  float* dis    = (float*)take((size_t)N * 4);
  int* rowptr   = (int*)take((size_t)(N + 1) * 4);
  int* fillpos  = (int*)take((size_t)N * 4);
  int* rptmp    = (int*)take((size_t)N * 4);
  int* col      = (int*)take((size_t)E * 4);
  int* bsum     = (int*)take(1024 * 4);
  int* boff     = (int*)take(1024 * 4);
  float* part   = (float*)take((size_t)512 * 256 * 4);
  float* ss     = (float*)take(256 * 4);

  const int nb256 = (N + 255) / 256;
  const int NB = (N + 1023) / 1024;
  const int nb64 = (N + 63) / 64;
  const int nbAgg = (N + 3) / 4;
  const int G = 512;

  // graph structure (recomputed every call; deterministic)
  k_deg_init<<<nb256, 256, 0, stream>>>(deg, N);
  k_deg_count<<<2048, 256, 0, stream>>>(dst, deg, E);
  k_dis<<<nb256, 256, 0, stream>>>(deg, dis, N);
  k_scan_block<<<NB, 1024, 0, stream>>>(deg, rptmp, bsum, N);
  k_scan_total<<<1, 32, 0, stream>>>(bsum, boff, NB);
  k_scan_finish<<<nb256, 256, 0, stream>>>(rptmp, boff, rowptr, fillpos, N, E);
  k_fill<<<2048, 256, 0, stream>>>(src, dst, fillpos, col, E);

  dim3 blk(256);

  // layer 1
  k_gemm_scale<128><<<dim3(nb64, 2), blk, 0, stream>>>(x, W1, dis, bufT, N);
  k_aggregate<128><<<nbAgg, blk, 0, stream>>>(bufT, rowptr, col, dis, b1, bufH, N);
  k_bn_partial<<<G, blk, 0, stream>>>(bufH, part, N);
  k_bn_final<<<1, 128, 0, stream>>>(part, g1, bt1, ss, G, N);
  k_bn_apply<<<2048, blk, 0, stream>>>(bufH, ss, (size_t)N * 32);

  // layer 2
  k_gemm_scale<128><<<dim3(nb64, 2), blk, 0, stream>>>(bufH, W2, dis, bufT, N);
  k_aggregate<128><<<nbAgg, blk, 0, stream>>>(bufT, rowptr, col, dis, b2, bufH, N);
  k_bn_partial<<<G, blk, 0, stream>>>(bufH, part, N);
  k_bn_final<<<1, 128, 0, stream>>>(part, g2, bt2, ss, G, N);
  k_bn_apply<<<2048, blk, 0, stream>>>(bufH, ss, (size_t)N * 32);

  // layer 3 (aggregate straight into d_out, f32)
  k_gemm_scale<64><<<dim3(nb64, 1), blk, 0, stream>>>(bufH, W3, dis, bufT, N);
  k_aggregate<64><<<nbAgg, blk, 0, stream>>>(bufT, rowptr, col, dis, b3, (float*)d_out, N);
}

// Round 2
// 825.584 us; speedup vs baseline: 1.2898x; 1.2898x over previous
//
#include <hip/hip_runtime.h>

#define NCH 128

// ---------------- degree / CSR build ----------------

__global__ __launch_bounds__(256) void k_deg_init(int* __restrict__ deg, int n) {
  int i = blockIdx.x * 256 + threadIdx.x;
  if (i < n) deg[i] = 1;  // self-loop
}

__global__ __launch_bounds__(256) void k_deg_count(const int* __restrict__ dst,
                                                   int* __restrict__ deg, int E) {
  int stride = gridDim.x * 256;
  for (int e = blockIdx.x * 256 + threadIdx.x; e < E; e += stride)
    atomicAdd(&deg[dst[e]], 1);
}

__global__ __launch_bounds__(256) void k_dis(const int* __restrict__ deg,
                                             float* __restrict__ dis, int n) {
  int i = blockIdx.x * 256 + threadIdx.x;
  if (i < n) dis[i] = rsqrtf((float)deg[i]);
}

__global__ __launch_bounds__(1024) void k_scan_block(const int* __restrict__ deg,
                                                     int* __restrict__ rptmp,
                                                     int* __restrict__ bsum, int n) {
  __shared__ int s[1024];
  int tid = threadIdx.x;
  int gid = blockIdx.x * 1024 + tid;
  int v = (gid < n) ? (deg[gid] - 1) : 0;  // in-degree excluding self-loop
  s[tid] = v;
  __syncthreads();
  for (int off = 1; off < 1024; off <<= 1) {
    int t = (tid >= off) ? s[tid - off] : 0;
    __syncthreads();
    s[tid] += t;
    __syncthreads();
  }
  if (gid < n) rptmp[gid] = s[tid] - v;  // exclusive
  if (tid == 1023) bsum[blockIdx.x] = s[1023];
}

__global__ void k_scan_total(const int* __restrict__ bsum, int* __restrict__ boff, int nb) {
  if (threadIdx.x == 0 && blockIdx.x == 0) {
    int acc = 0;
    for (int b = 0; b < nb; ++b) { boff[b] = acc; acc += bsum[b]; }
  }
}

__global__ __launch_bounds__(256) void k_scan_finish(const int* __restrict__ rptmp,
                                                     const int* __restrict__ boff,
                                                     int* __restrict__ rowptr,
                                                     int* __restrict__ fillpos, int n, int E) {
  int i = blockIdx.x * 256 + threadIdx.x;
  if (i < n) {
    int v = rptmp[i] + boff[i >> 10];
    rowptr[i] = v;
    fillpos[i] = v;
  }
  if (i == 0) rowptr[n] = E;
}

__global__ __launch_bounds__(256) void k_fill(const int* __restrict__ src,
                                              const int* __restrict__ dst,
                                              int* __restrict__ fillpos,
                                              int* __restrict__ col, int E) {
  int stride = gridDim.x * 256;
  for (int e = blockIdx.x * 256 + threadIdx.x; e < E; e += stride) {
    int p = atomicAdd(&fillpos[dst[e]], 1);
    col[p] = src[e];
  }
}

// ---------------- GEMM: T[n][c] = dis[n] * sum_k f(X[n][k])*W[k][c] ----------------
// f = identity, or fused BN+ReLU (training-mode, precomputed scale/shift in ss)
// tile 64 rows x 64 cols, 256 threads, thread = 4 rows x 4 cols

template <int COUT, bool BNRELU>
__global__ __launch_bounds__(256) void k_gemm_scale(const float* __restrict__ X,
                                                    const float* __restrict__ W,
                                                    const float* __restrict__ dis,
                                                    const float* __restrict__ ss,
                                                    float* __restrict__ T, int nrows) {
  __shared__ float xs[64][132];   // row-major x tile, padded (132*4 % 16 == 0)
  __shared__ float ws[128][68];   // k x col tile, padded
  const int tid = threadIdx.x;
  const int row0 = blockIdx.x * 64;
  const int c0 = blockIdx.y * 64;

#pragma unroll
  for (int i = 0; i < 8; ++i) {
    int idx = tid + i * 256;       // 0..2047 over 64 rows x 32 k-quads
    int r = idx >> 5, kk = idx & 31;
    int row = row0 + r;
    float4 v = make_float4(0.f, 0.f, 0.f, 0.f);
    if (row < nrows) v = *reinterpret_cast<const float4*>(X + (size_t)row * NCH + kk * 4);
    if constexpr (BNRELU) {
      float4 sc = *reinterpret_cast<const float4*>(&ss[kk * 4]);
      float4 sh = *reinterpret_cast<const float4*>(&ss[128 + kk * 4]);
      v.x = fmaxf(fmaf(v.x, sc.x, sh.x), 0.f);
      v.y = fmaxf(fmaf(v.y, sc.y, sh.y), 0.f);
      v.z = fmaxf(fmaf(v.z, sc.z, sh.z), 0.f);
      v.w = fmaxf(fmaf(v.w, sc.w, sh.w), 0.f);
    }
    *reinterpret_cast<float4*>(&xs[r][kk * 4]) = v;
  }
#pragma unroll
  for (int i = 0; i < 8; ++i) {
    int idx = tid + i * 256;       // 0..2047 over 128 k x 16 col-quads
    int k = idx >> 4, q = idx & 15;
    float4 v = *reinterpret_cast<const float4*>(W + (size_t)k * COUT + c0 + q * 4);
    *reinterpret_cast<float4*>(&ws[k][q * 4]) = v;
  }
  __syncthreads();

  const int tc = tid & 15, tr = tid >> 4;
  float4 acc0 = make_float4(0.f, 0.f, 0.f, 0.f);
  float4 acc1 = acc0, acc2 = acc0, acc3 = acc0;

#define FMA4(ACC, S, B)                                                                \
  ACC.x = fmaf(S, B.x, ACC.x); ACC.y = fmaf(S, B.y, ACC.y);                            \
  ACC.z = fmaf(S, B.z, ACC.z); ACC.w = fmaf(S, B.w, ACC.w)

#pragma unroll 8
  for (int k = 0; k < 128; k += 4) {
    float4 A0 = *reinterpret_cast<const float4*>(&xs[4 * tr + 0][k]);
    float4 A1 = *reinterpret_cast<const float4*>(&xs[4 * tr + 1][k]);
    float4 A2 = *reinterpret_cast<const float4*>(&xs[4 * tr + 2][k]);
    float4 A3 = *reinterpret_cast<const float4*>(&xs[4 * tr + 3][k]);
    float4 B0 = *reinterpret_cast<const float4*>(&ws[k + 0][4 * tc]);
    float4 B1 = *reinterpret_cast<const float4*>(&ws[k + 1][4 * tc]);
    float4 B2 = *reinterpret_cast<const float4*>(&ws[k + 2][4 * tc]);
    float4 B3 = *reinterpret_cast<const float4*>(&ws[k + 3][4 * tc]);
    FMA4(acc0, A0.x, B0); FMA4(acc0, A0.y, B1); FMA4(acc0, A0.z, B2); FMA4(acc0, A0.w, B3);
    FMA4(acc1, A1.x, B0); FMA4(acc1, A1.y, B1); FMA4(acc1, A1.z, B2); FMA4(acc1, A1.w, B3);
    FMA4(acc2, A2.x, B0); FMA4(acc2, A2.y, B1); FMA4(acc2, A2.z, B2); FMA4(acc2, A2.w, B3);
    FMA4(acc3, A3.x, B0); FMA4(acc3, A3.y, B1); FMA4(acc3, A3.z, B2); FMA4(acc3, A3.w, B3);
  }
#undef FMA4

  float4 accs[4] = {acc0, acc1, acc2, acc3};
#pragma unroll
  for (int i = 0; i < 4; ++i) {
    int row = row0 + 4 * tr + i;
    if (row < nrows) {
      float d = dis[row];
      float4 o;
      o.x = accs[i].x * d; o.y = accs[i].y * d; o.z = accs[i].z * d; o.w = accs[i].w * d;
      *reinterpret_cast<float4*>(T + (size_t)row * COUT + c0 + 4 * tc) = o;
    }
  }
}

// ---------------- pull aggregation: OUT[i] = dis[i]*(T'[i] + sum_{e in(i)} T'[src_e]) + b ----------------

template <int C>
__global__ __launch_bounds__(256) void k_aggregate(const float* __restrict__ T,
                                                   const int* __restrict__ rowptr,
                                                   const int* __restrict__ col,
                                                   const float* __restrict__ dis,
                                                   const float* __restrict__ bias,
                                                   float* __restrict__ OUT, int n) {
  const int lane = threadIdx.x & 63;
  const int node = blockIdx.x * 4 + (threadIdx.x >> 6);
  if (node >= n) return;
  const int beg = rowptr[node], end = rowptr[node + 1];

  if constexpr (C == 128) {
    float2 acc = *reinterpret_cast<const float2*>(T + (size_t)node * 128 + lane * 2);
    for (int e = beg; e < end;) {
      int cnt = end - e;
      if (cnt > 64) cnt = 64;
      int sl = (e + lane < end) ? col[e + lane] : 0;
      for (int j = 0; j < cnt; ++j) {
        int s = __shfl(sl, j);
        float2 v = *reinterpret_cast<const float2*>(T + (size_t)s * 128 + lane * 2);
        acc.x += v.x;
        acc.y += v.y;
      }
      e += cnt;
    }
    float d = dis[node];
    float2 o;
    o.x = fmaf(acc.x, d, bias[lane * 2]);
    o.y = fmaf(acc.y, d, bias[lane * 2 + 1]);
    *reinterpret_cast<float2*>(OUT + (size_t)node * 128 + lane * 2) = o;
  } else {
    float acc = T[(size_t)node * 64 + lane];
    for (int e = beg; e < end;) {
      int cnt = end - e;
      if (cnt > 64) cnt = 64;
      int sl = (e + lane < end) ? col[e + lane] : 0;
      for (int j = 0; j < cnt; ++j) {
        int s = __shfl(sl, j);
        acc += T[(size_t)s * 64 + lane];
      }
      e += cnt;
    }
    float d = dis[node];
    OUT[(size_t)node * 64 + lane] = fmaf(acc, d, bias[lane]);
  }
}

// ---------------- BatchNorm (training-mode batch stats): partial + final ----------------

__global__ __launch_bounds__(256) void k_bn_partial(const float* __restrict__ H,
                                                    float* __restrict__ part, int nrows) {
  const int c = threadIdx.x & 127;
  const int half = threadIdx.x >> 7;
  float s = 0.f, s2 = 0.f;
  for (int r = blockIdx.x * 2 + half; r < nrows; r += gridDim.x * 2) {
    float v = H[(size_t)r * 128 + c];
    s += v;
    s2 += v * v;
  }
  __shared__ float ls[256], ls2[256];
  ls[threadIdx.x] = s;
  ls2[threadIdx.x] = s2;
  __syncthreads();
  if (half == 0) {
    part[(size_t)blockIdx.x * 256 + c] = ls[c] + ls[c + 128];
    part[(size_t)blockIdx.x * 256 + 128 + c] = ls2[c] + ls2[c + 128];
  }
}

// 1024 threads: thread (c, grp) strides over partial blocks; LDS tree over 8 groups.
__global__ __launch_bounds__(1024) void k_bn_final(const float* __restrict__ part,
                                                   const float* __restrict__ g,
                                                   const float* __restrict__ bt,
                                                   float* __restrict__ ss, int G, int nrows) {
  const int c = threadIdx.x & 127;
  const int grp = threadIdx.x >> 7;  // 0..7
  float S = 0.f, S2 = 0.f;
  for (int b = grp; b < G; b += 8) {
    S += part[(size_t)b * 256 + c];
    S2 += part[(size_t)b * 256 + 128 + c];
  }
  __shared__ float sS[8][128], sS2[8][128];
  sS[grp][c] = S;
  sS2[grp][c] = S2;
  __syncthreads();
  if (grp == 0) {
#pragma unroll
    for (int i = 1; i < 8; ++i) { S += sS[i][c]; S2 += sS2[i][c]; }
    float inv_n = 1.f / (float)nrows;
    float mean = S * inv_n;
    float var = S2 * inv_n - mean * mean;
    float sc = g[c] * rsqrtf(var + 1e-5f);
    ss[c] = sc;
    ss[128 + c] = bt[c] - mean * sc;
  }
}

// ---------------- driver ----------------

extern "C" void kernel_launch(void* const* d_in, const int* in_sizes, int n_in,
                              void* d_out, int out_size, void* d_ws, size_t ws_size,
                              hipStream_t stream) {
  const float* x  = (const float*)d_in[0];
  const int* ei   = (const int*)d_in[1];
  const float* W1 = (const float*)d_in[2];
  const float* b1 = (const float*)d_in[3];
  const float* g1 = (const float*)d_in[4];
  const float* bt1= (const float*)d_in[5];
  const float* W2 = (const float*)d_in[6];
  const float* b2 = (const float*)d_in[7];
  const float* g2 = (const float*)d_in[8];
  const float* bt2= (const float*)d_in[9];
  const float* W3 = (const float*)d_in[10];
  const float* b3 = (const float*)d_in[11];

  const int N = in_sizes[0] / NCH;
  const int E = in_sizes[1] / 2;
  const int* src = ei;
  const int* dst = ei + E;

  char* p = (char*)d_ws;
  auto take = [&](size_t bytes) -> char* {
    char* r = p;
    p += (bytes + 255) & ~(size_t)255;
    return r;
  };
  float* bufT   = (float*)take((size_t)N * 128 * 4);
  float* bufH   = (float*)take((size_t)N * 128 * 4);
  int* deg      = (int*)take((size_t)N * 4);
  float* dis    = (float*)take((size_t)N * 4);
  int* rowptr   = (int*)take((size_t)(N + 1) * 4);
  int* fillpos  = (int*)take((size_t)N * 4);
  int* rptmp    = (int*)take((size_t)N * 4);
  int* col      = (int*)take((size_t)E * 4);
  int* bsum     = (int*)take(1024 * 4);
  int* boff     = (int*)take(1024 * 4);
  float* part   = (float*)take((size_t)512 * 256 * 4);
  float* ss1    = (float*)take(256 * 4);
  float* ss2    = (float*)take(256 * 4);

  const int nb256 = (N + 255) / 256;
  const int NB = (N + 1023) / 1024;
  const int nb64 = (N + 63) / 64;
  const int nbAgg = (N + 3) / 4;
  const int G = 512;

  // graph structure (recomputed every call; deterministic)
  k_deg_init<<<nb256, 256, 0, stream>>>(deg, N);
  k_deg_count<<<2048, 256, 0, stream>>>(dst, deg, E);
  k_dis<<<nb256, 256, 0, stream>>>(deg, dis, N);
  k_scan_block<<<NB, 1024, 0, stream>>>(deg, rptmp, bsum, N);
  k_scan_total<<<1, 32, 0, stream>>>(bsum, boff, NB);
  k_scan_finish<<<nb256, 256, 0, stream>>>(rptmp, boff, rowptr, fillpos, N, E);
  k_fill<<<2048, 256, 0, stream>>>(src, dst, fillpos, col, E);

  dim3 blk(256);

  // layer 1
  k_gemm_scale<128, false><<<dim3(nb64, 2), blk, 0, stream>>>(x, W1, dis, nullptr, bufT, N);
  k_aggregate<128><<<nbAgg, blk, 0, stream>>>(bufT, rowptr, col, dis, b1, bufH, N);
  k_bn_partial<<<G, blk, 0, stream>>>(bufH, part, N);
  k_bn_final<<<1, 1024, 0, stream>>>(part, g1, bt1, ss1, G, N);

  // layer 2 (BN1+ReLU fused into GEMM X load)
  k_gemm_scale<128, true><<<dim3(nb64, 2), blk, 0, stream>>>(bufH, W2, dis, ss1, bufT, N);
  k_aggregate<128><<<nbAgg, blk, 0, stream>>>(bufT, rowptr, col, dis, b2, bufH, N);
  k_bn_partial<<<G, blk, 0, stream>>>(bufH, part, N);
  k_bn_final<<<1, 1024, 0, stream>>>(part, g2, bt2, ss2, G, N);

  // layer 3 (BN2+ReLU fused; aggregate straight into d_out, f32)
  k_gemm_scale<64, true><<<dim3(nb64, 1), blk, 0, stream>>>(bufH, W3, dis, ss2, bufT, N);
  k_aggregate<64><<<nbAgg, blk, 0, stream>>>(bufT, rowptr, col, dis, b3, (float*)d_out, N);
}

// Round 6
// 785.171 us; speedup vs baseline: 1.3562x; 1.0515x over previous
//
#include <hip/hip_runtime.h>

#define NCH 128

// ---------------- degree / CSR build ----------------

__global__ __launch_bounds__(256) void k_deg_init(int* __restrict__ deg, int n) {
  int i = blockIdx.x * 256 + threadIdx.x;
  if (i < n) deg[i] = 1;  // self-loop
}

__global__ __launch_bounds__(256) void k_deg_count(const int* __restrict__ dst,
                                                   int* __restrict__ deg, int E) {
  int stride = gridDim.x * 256;
  for (int e = blockIdx.x * 256 + threadIdx.x; e < E; e += stride)
    atomicAdd(&deg[dst[e]], 1);
}

__global__ __launch_bounds__(256) void k_dis(const int* __restrict__ deg,
                                             float* __restrict__ dis, int n) {
  int i = blockIdx.x * 256 + threadIdx.x;
  if (i < n) dis[i] = rsqrtf((float)deg[i]);
}

__global__ __launch_bounds__(1024) void k_scan_block(const int* __restrict__ deg,
                                                     int* __restrict__ rptmp,
                                                     int* __restrict__ bsum, int n) {
  __shared__ int s[1024];
  int tid = threadIdx.x;
  int gid = blockIdx.x * 1024 + tid;
  int v = (gid < n) ? (deg[gid] - 1) : 0;  // in-degree excluding self-loop
  s[tid] = v;
  __syncthreads();
  for (int off = 1; off < 1024; off <<= 1) {
    int t = (tid >= off) ? s[tid - off] : 0;
    __syncthreads();
    s[tid] += t;
    __syncthreads();
  }
  if (gid < n) rptmp[gid] = s[tid] - v;  // exclusive
  if (tid == 1023) bsum[blockIdx.x] = s[1023];
}

__global__ void k_scan_total(const int* __restrict__ bsum, int* __restrict__ boff, int nb) {
  if (threadIdx.x == 0 && blockIdx.x == 0) {
    int acc = 0;
    for (int b = 0; b < nb; ++b) { boff[b] = acc; acc += bsum[b]; }
  }
}

__global__ __launch_bounds__(256) void k_scan_finish(const int* __restrict__ rptmp,
                                                     const int* __restrict__ boff,
                                                     int* __restrict__ rowptr,
                                                     int* __restrict__ fillpos, int n, int E) {
  int i = blockIdx.x * 256 + threadIdx.x;
  if (i < n) {
    int v = rptmp[i] + boff[i >> 10];
    rowptr[i] = v;
    fillpos[i] = v;
  }
  if (i == 0) rowptr[n] = E;
}

__global__ __launch_bounds__(256) void k_fill(const int* __restrict__ src,
                                              const int* __restrict__ dst,
                                              int* __restrict__ fillpos,
                                              int* __restrict__ col, int E) {
  int stride = gridDim.x * 256;
  for (int e = blockIdx.x * 256 + threadIdx.x; e < E; e += stride) {
    int p = atomicAdd(&fillpos[dst[e]], 1);
    col[p] = src[e];
  }
}

// ---------------- GEMM: T[n][c] = dis[n] * sum_k f(X[n][k])*W[k][c] ----------------
// f = identity, or fused BN+ReLU (training-mode, precomputed scale/shift in ss)
// tile 64 rows x 64 cols, 256 threads, thread = 4 rows x 4 cols

template <int COUT, bool BNRELU>
__global__ __launch_bounds__(256) void k_gemm_scale(const float* __restrict__ X,
                                                    const float* __restrict__ W,
                                                    const float* __restrict__ dis,
                                                    const float* __restrict__ ss,
                                                    float* __restrict__ T, int nrows) {
  __shared__ float xs[64][132];   // row-major x tile, padded (132*4 % 16 == 0)
  __shared__ float ws[128][68];   // k x col tile, padded
  const int tid = threadIdx.x;
  const int row0 = blockIdx.x * 64;
  const int c0 = blockIdx.y * 64;

#pragma unroll
  for (int i = 0; i < 8; ++i) {
    int idx = tid + i * 256;       // 0..2047 over 64 rows x 32 k-quads
    int r = idx >> 5, kk = idx & 31;
    int row = row0 + r;
    float4 v = make_float4(0.f, 0.f, 0.f, 0.f);
    if (row < nrows) v = *reinterpret_cast<const float4*>(X + (size_t)row * NCH + kk * 4);
    if constexpr (BNRELU) {
      float4 sc = *reinterpret_cast<const float4*>(&ss[kk * 4]);
      float4 sh = *reinterpret_cast<const float4*>(&ss[128 + kk * 4]);
      v.x = fmaxf(fmaf(v.x, sc.x, sh.x), 0.f);
      v.y = fmaxf(fmaf(v.y, sc.y, sh.y), 0.f);
      v.z = fmaxf(fmaf(v.z, sc.z, sh.z), 0.f);
      v.w = fmaxf(fmaf(v.w, sc.w, sh.w), 0.f);
    }
    *reinterpret_cast<float4*>(&xs[r][kk * 4]) = v;
  }
#pragma unroll
  for (int i = 0; i < 8; ++i) {
    int idx = tid + i * 256;       // 0..2047 over 128 k x 16 col-quads
    int k = idx >> 4, q = idx & 15;
    float4 v = *reinterpret_cast<const float4*>(W + (size_t)k * COUT + c0 + q * 4);
    *reinterpret_cast<float4*>(&ws[k][q * 4]) = v;
  }
  __syncthreads();

  const int tc = tid & 15, tr = tid >> 4;
  float4 acc0 = make_float4(0.f, 0.f, 0.f, 0.f);
  float4 acc1 = acc0, acc2 = acc0, acc3 = acc0;

#define FMA4(ACC, S, B)                                                                \
  ACC.x = fmaf(S, B.x, ACC.x); ACC.y = fmaf(S, B.y, ACC.y);                            \
  ACC.z = fmaf(S, B.z, ACC.z); ACC.w = fmaf(S, B.w, ACC.w)

#pragma unroll 8
  for (int k = 0; k < 128; k += 4) {
    float4 A0 = *reinterpret_cast<const float4*>(&xs[4 * tr + 0][k]);
    float4 A1 = *reinterpret_cast<const float4*>(&xs[4 * tr + 1][k]);
    float4 A2 = *reinterpret_cast<const float4*>(&xs[4 * tr + 2][k]);
    float4 A3 = *reinterpret_cast<const float4*>(&xs[4 * tr + 3][k]);
    float4 B0 = *reinterpret_cast<const float4*>(&ws[k + 0][4 * tc]);
    float4 B1 = *reinterpret_cast<const float4*>(&ws[k + 1][4 * tc]);
    float4 B2 = *reinterpret_cast<const float4*>(&ws[k + 2][4 * tc]);
    float4 B3 = *reinterpret_cast<const float4*>(&ws[k + 3][4 * tc]);
    FMA4(acc0, A0.x, B0); FMA4(acc0, A0.y, B1); FMA4(acc0, A0.z, B2); FMA4(acc0, A0.w, B3);
    FMA4(acc1, A1.x, B0); FMA4(acc1, A1.y, B1); FMA4(acc1, A1.z, B2); FMA4(acc1, A1.w, B3);
    FMA4(acc2, A2.x, B0); FMA4(acc2, A2.y, B1); FMA4(acc2, A2.z, B2); FMA4(acc2, A2.w, B3);
    FMA4(acc3, A3.x, B0); FMA4(acc3, A3.y, B1); FMA4(acc3, A3.z, B2); FMA4(acc3, A3.w, B3);
  }
#undef FMA4

  float4 accs[4] = {acc0, acc1, acc2, acc3};
#pragma unroll
  for (int i = 0; i < 4; ++i) {
    int row = row0 + 4 * tr + i;
    if (row < nrows) {
      float d = dis[row];
      float4 o;
      o.x = accs[i].x * d; o.y = accs[i].y * d; o.z = accs[i].z * d; o.w = accs[i].w * d;
      *reinterpret_cast<float4*>(T + (size_t)row * COUT + c0 + 4 * tc) = o;
    }
  }
}

// ---------------- pull aggregation: OUT[i] = dis[i]*(T[i] + sum_{e in(i)} T[src_e]) + b ----
// wave per node; 32 lanes x float4 = one 512B row; 2 sources concurrently.
// NOTE: every __shfl is executed at FULL-WAVE scope — a __shfl inside a
// divergent branch reads garbage when the source lane is exec-masked off
// (ds_bpermute sources only active lanes). That was the round-3/4/5 bug.

__global__ __launch_bounds__(256) void k_aggregate128(const float* __restrict__ T,
                                                      const int* __restrict__ rowptr,
                                                      const int* __restrict__ col,
                                                      const float* __restrict__ dis,
                                                      const float* __restrict__ bias,
                                                      float* __restrict__ OUT, int n) {
  const int lane = threadIdx.x & 63;
  const int node = blockIdx.x * 4 + (threadIdx.x >> 6);
  if (node >= n) return;
  const int sub = lane >> 5;   // which of the 2 concurrent sources
  const int cl = lane & 31;    // channel quad: 4*cl .. 4*cl+3
  const int beg = rowptr[node], end = rowptr[node + 1];

  float4 acc = make_float4(0.f, 0.f, 0.f, 0.f);
  if (sub == 0) {
    float4 v = *reinterpret_cast<const float4*>(T + (size_t)node * 128 + cl * 4);
    acc.x += v.x; acc.y += v.y; acc.z += v.z; acc.w += v.w;
  }
  for (int e = beg; e < end;) {
    int cnt = end - e;
    if (cnt > 64) cnt = 64;
    int sl = (e + lane < end) ? col[e + lane] : 0;
    int j = 0;
    for (; j + 4 <= cnt; j += 4) {
      int s0 = __shfl(sl, j + sub);
      int s1 = __shfl(sl, j + 2 + sub);
      float4 v0 = *reinterpret_cast<const float4*>(T + (size_t)s0 * 128 + cl * 4);
      float4 v1 = *reinterpret_cast<const float4*>(T + (size_t)s1 * 128 + cl * 4);
      acc.x += v0.x + v1.x; acc.y += v0.y + v1.y;
      acc.z += v0.z + v1.z; acc.w += v0.w + v1.w;
    }
    if (j + 2 <= cnt) {
      int s = __shfl(sl, j + sub);          // full-wave shfl
      float4 v = *reinterpret_cast<const float4*>(T + (size_t)s * 128 + cl * 4);
      acc.x += v.x; acc.y += v.y; acc.z += v.z; acc.w += v.w;
      j += 2;
    }
    if (j < cnt) {
      int s = __shfl(sl, j);                // full-wave shfl (bugfix: was inside sub==0)
      if (sub == 0) {
        float4 v = *reinterpret_cast<const float4*>(T + (size_t)s * 128 + cl * 4);
        acc.x += v.x; acc.y += v.y; acc.z += v.z; acc.w += v.w;
      }
    }
    e += cnt;
  }
  // combine the two halves
  acc.x += __shfl_xor(acc.x, 32);
  acc.y += __shfl_xor(acc.y, 32);
  acc.z += __shfl_xor(acc.z, 32);
  acc.w += __shfl_xor(acc.w, 32);
  if (sub == 0) {
    float d = dis[node];
    float4 b = *reinterpret_cast<const float4*>(&bias[cl * 4]);
    float4 o;
    o.x = fmaf(acc.x, d, b.x); o.y = fmaf(acc.y, d, b.y);
    o.z = fmaf(acc.z, d, b.z); o.w = fmaf(acc.w, d, b.w);
    *reinterpret_cast<float4*>(OUT + (size_t)node * 128 + cl * 4) = o;
  }
}

__global__ __launch_bounds__(256) void k_aggregate64(const float* __restrict__ T,
                                                     const int* __restrict__ rowptr,
                                                     const int* __restrict__ col,
                                                     const float* __restrict__ dis,
                                                     const float* __restrict__ bias,
                                                     float* __restrict__ OUT, int n) {
  const int lane = threadIdx.x & 63;
  const int node = blockIdx.x * 4 + (threadIdx.x >> 6);
  if (node >= n) return;
  const int sub = lane >> 5;
  const int cl = lane & 31;    // channel pair 2*cl, 2*cl+1
  const int beg = rowptr[node], end = rowptr[node + 1];

  float2 acc = make_float2(0.f, 0.f);
  if (sub == 0) {
    float2 v = *reinterpret_cast<const float2*>(T + (size_t)node * 64 + cl * 2);
    acc.x += v.x; acc.y += v.y;
  }
  for (int e = beg; e < end;) {
    int cnt = end - e;
    if (cnt > 64) cnt = 64;
    int sl = (e + lane < end) ? col[e + lane] : 0;
    int j = 0;
    for (; j + 4 <= cnt; j += 4) {
      int s0 = __shfl(sl, j + sub);
      int s1 = __shfl(sl, j + 2 + sub);
      float2 v0 = *reinterpret_cast<const float2*>(T + (size_t)s0 * 64 + cl * 2);
      float2 v1 = *reinterpret_cast<const float2*>(T + (size_t)s1 * 64 + cl * 2);
      acc.x += v0.x + v1.x; acc.y += v0.y + v1.y;
    }
    if (j + 2 <= cnt) {
      int s = __shfl(sl, j + sub);          // full-wave shfl
      float2 v = *reinterpret_cast<const float2*>(T + (size_t)s * 64 + cl * 2);
      acc.x += v.x; acc.y += v.y;
      j += 2;
    }
    if (j < cnt) {
      int s = __shfl(sl, j);                // full-wave shfl (bugfix: was inside sub==0)
      if (sub == 0) {
        float2 v = *reinterpret_cast<const float2*>(T + (size_t)s * 64 + cl * 2);
        acc.x += v.x; acc.y += v.y;
      }
    }
    e += cnt;
  }
  acc.x += __shfl_xor(acc.x, 32);
  acc.y += __shfl_xor(acc.y, 32);
  if (sub == 0) {
    float d = dis[node];
    float2 o;
    o.x = fmaf(acc.x, d, bias[cl * 2]);
    o.y = fmaf(acc.y, d, bias[cl * 2 + 1]);
    *reinterpret_cast<float2*>(OUT + (size_t)node * 64 + cl * 2) = o;
  }
}

// ---------------- BatchNorm (training-mode batch stats): partial + final ----------------

__global__ __launch_bounds__(256) void k_bn_partial(const float* __restrict__ H,
                                                    float* __restrict__ part, int nrows) {
  const int c = threadIdx.x & 127;
  const int half = threadIdx.x >> 7;
  float s = 0.f, s2 = 0.f;
  for (int r = blockIdx.x * 2 + half; r < nrows; r += gridDim.x * 2) {
    float v = H[(size_t)r * 128 + c];
    s += v;
    s2 += v * v;
  }
  __shared__ float ls[256], ls2[256];
  ls[threadIdx.x] = s;
  ls2[threadIdx.x] = s2;
  __syncthreads();
  if (half == 0) {
    part[(size_t)blockIdx.x * 256 + c] = ls[c] + ls[c + 128];
    part[(size_t)blockIdx.x * 256 + 128 + c] = ls2[c] + ls2[c + 128];
  }
}

// 1024 threads: thread (c, grp) strides over partial blocks; LDS tree over 8 groups.
__global__ __launch_bounds__(1024) void k_bn_final(const float* __restrict__ part,
                                                   const float* __restrict__ g,
                                                   const float* __restrict__ bt,
                                                   float* __restrict__ ss, int G, int nrows) {
  const int c = threadIdx.x & 127;
  const int grp = threadIdx.x >> 7;  // 0..7
  float S = 0.f, S2 = 0.f;
  for (int b = grp; b < G; b += 8) {
    S += part[(size_t)b * 256 + c];
    S2 += part[(size_t)b * 256 + 128 + c];
  }
  __shared__ float sS[8][128], sS2[8][128];
  sS[grp][c] = S;
  sS2[grp][c] = S2;
  __syncthreads();
  if (grp == 0) {
#pragma unroll
    for (int i = 1; i < 8; ++i) { S += sS[i][c]; S2 += sS2[i][c]; }
    float inv_n = 1.f / (float)nrows;
    float mean = S * inv_n;
    float var = S2 * inv_n - mean * mean;
    float sc = g[c] * rsqrtf(var + 1e-5f);
    ss[c] = sc;
    ss[128 + c] = bt[c] - mean * sc;
  }
}

// ---------------- driver ----------------

extern "C" void kernel_launch(void* const* d_in, const int* in_sizes, int n_in,
                              void* d_out, int out_size, void* d_ws, size_t ws_size,
                              hipStream_t stream) {
  const float* x  = (const float*)d_in[0];
  const int* ei   = (const int*)d_in[1];
  const float* W1 = (const float*)d_in[2];
  const float* b1 = (const float*)d_in[3];
  const float* g1 = (const float*)d_in[4];
  const float* bt1= (const float*)d_in[5];
  const float* W2 = (const float*)d_in[6];
  const float* b2 = (const float*)d_in[7];
  const float* g2 = (const float*)d_in[8];
  const float* bt2= (const float*)d_in[9];
  const float* W3 = (const float*)d_in[10];
  const float* b3 = (const float*)d_in[11];

  const int N = in_sizes[0] / NCH;
  const int E = in_sizes[1] / 2;
  const int* src = ei;
  const int* dst = ei + E;

  char* p = (char*)d_ws;
  auto take = [&](size_t bytes) -> char* {
    char* r = p;
    p += (bytes + 255) & ~(size_t)255;
    return r;
  };
  float* bufT   = (float*)take((size_t)N * 128 * 4);
  float* bufH   = (float*)take((size_t)N * 128 * 4);
  int* deg      = (int*)take((size_t)N * 4);
  float* dis    = (float*)take((size_t)N * 4);
  int* rowptr   = (int*)take((size_t)(N + 1) * 4);
  int* fillpos  = (int*)take((size_t)N * 4);
  int* rptmp    = (int*)take((size_t)N * 4);
  int* col      = (int*)take((size_t)E * 4);
  int* bsum     = (int*)take(1024 * 4);
  int* boff     = (int*)take(1024 * 4);
  float* part   = (float*)take((size_t)512 * 256 * 4);
  float* ss1    = (float*)take(256 * 4);
  float* ss2    = (float*)take(256 * 4);

  const int nb256 = (N + 255) / 256;
  const int NB = (N + 1023) / 1024;
  const int nb64 = (N + 63) / 64;
  const int nbAgg = (N + 3) / 4;
  const int G = 512;

  // graph structure (recomputed every call; deterministic)
  k_deg_init<<<nb256, 256, 0, stream>>>(deg, N);
  k_deg_count<<<2048, 256, 0, stream>>>(dst, deg, E);
  k_dis<<<nb256, 256, 0, stream>>>(deg, dis, N);
  k_scan_block<<<NB, 1024, 0, stream>>>(deg, rptmp, bsum, N);
  k_scan_total<<<1, 32, 0, stream>>>(bsum, boff, NB);
  k_scan_finish<<<nb256, 256, 0, stream>>>(rptmp, boff, rowptr, fillpos, N, E);
  k_fill<<<2048, 256, 0, stream>>>(src, dst, fillpos, col, E);

  dim3 blk(256);

  // layer 1
  k_gemm_scale<128, false><<<dim3(nb64, 2), blk, 0, stream>>>(x, W1, dis, nullptr, bufT, N);
  k_aggregate128<<<nbAgg, blk, 0, stream>>>(bufT, rowptr, col, dis, b1, bufH, N);
  k_bn_partial<<<G, blk, 0, stream>>>(bufH, part, N);
  k_bn_final<<<1, 1024, 0, stream>>>(part, g1, bt1, ss1, G, N);

  // layer 2 (BN1+ReLU fused into GEMM X load)
  k_gemm_scale<128, true><<<dim3(nb64, 2), blk, 0, stream>>>(bufH, W2, dis, ss1, bufT, N);
  k_aggregate128<<<nbAgg, blk, 0, stream>>>(bufT, rowptr, col, dis, b2, bufH, N);
  k_bn_partial<<<G, blk, 0, stream>>>(bufH, part, N);
  k_bn_final<<<1, 1024, 0, stream>>>(part, g2, bt2, ss2, G, N);

  // layer 3 (BN2+ReLU fused; aggregate straight into d_out, f32)
  k_gemm_scale<64, true><<<dim3(nb64, 1), blk, 0, stream>>>(bufH, W3, dis, ss2, bufT, N);
  k_aggregate64<<<nbAgg, blk, 0, stream>>>(bufT, rowptr, col, dis, b3, (float*)d_out, N);
}

// Round 7
// 501.375 us; speedup vs baseline: 2.1239x; 1.5660x over previous
//
#include <hip/hip_runtime.h>
#include <hip/hip_fp16.h>

#define NCH 128

// ---------------- degree / CSR build ----------------

__global__ __launch_bounds__(256) void k_deg_init(int* __restrict__ deg, int n) {
  int i = blockIdx.x * 256 + threadIdx.x;
  if (i < n) deg[i] = 1;  // self-loop
}

// counts in-degree AND records each edge's arrival rank (1-based, after the self-loop init)
__global__ __launch_bounds__(256) void k_deg_count(const int* __restrict__ dst,
                                                   int* __restrict__ deg,
                                                   int* __restrict__ rank, int E) {
  int stride = gridDim.x * 256;
  for (int e = blockIdx.x * 256 + threadIdx.x; e < E; e += stride)
    rank[e] = atomicAdd(&deg[dst[e]], 1);
}

__global__ __launch_bounds__(256) void k_dis(const int* __restrict__ deg,
                                             float* __restrict__ dis, int n) {
  int i = blockIdx.x * 256 + threadIdx.x;
  if (i < n) dis[i] = rsqrtf((float)deg[i]);
}

__global__ __launch_bounds__(1024) void k_scan_block(const int* __restrict__ deg,
                                                     int* __restrict__ rptmp,
                                                     int* __restrict__ bsum, int n) {
  __shared__ int s[1024];
  int tid = threadIdx.x;
  int gid = blockIdx.x * 1024 + tid;
  int v = (gid < n) ? (deg[gid] - 1) : 0;  // in-degree excluding self-loop
  s[tid] = v;
  __syncthreads();
  for (int off = 1; off < 1024; off <<= 1) {
    int t = (tid >= off) ? s[tid - off] : 0;
    __syncthreads();
    s[tid] += t;
    __syncthreads();
  }
  if (gid < n) rptmp[gid] = s[tid] - v;  // exclusive
  if (tid == 1023) bsum[blockIdx.x] = s[1023];
}

__global__ __launch_bounds__(1024) void k_scan_total(const int* __restrict__ bsum,
                                                     int* __restrict__ boff, int nb) {
  __shared__ int s[1024];
  int t = threadIdx.x;
  int v = (t < nb) ? bsum[t] : 0;
  s[t] = v;
  __syncthreads();
  for (int off = 1; off < 1024; off <<= 1) {
    int u = (t >= off) ? s[t - off] : 0;
    __syncthreads();
    s[t] += u;
    __syncthreads();
  }
  if (t < nb) boff[t] = s[t] - v;  // exclusive
}

__global__ __launch_bounds__(256) void k_scan_finish(const int* __restrict__ rptmp,
                                                     const int* __restrict__ boff,
                                                     int* __restrict__ rowptr, int n, int E) {
  int i = blockIdx.x * 256 + threadIdx.x;
  if (i < n) rowptr[i] = rptmp[i] + boff[i >> 10];
  if (i == 0) rowptr[n] = E;
}

// atomic-free fill: position comes from rowptr + (rank-1)
__global__ __launch_bounds__(256) void k_fill(const int* __restrict__ src,
                                              const int* __restrict__ dst,
                                              const int* __restrict__ rowptr,
                                              const int* __restrict__ rank,
                                              int* __restrict__ col, int E) {
  int stride = gridDim.x * 256;
  for (int e = blockIdx.x * 256 + threadIdx.x; e < E; e += stride) {
    int p = rowptr[dst[e]] + rank[e] - 1;
    col[p] = src[e];
  }
}

// ---------------- GEMM: T[n][c] = fp16( dis[n] * sum_k f(X[n][k])*W[k][c] ) ----------------
// f = identity (f32 X, layer 1) or fused BN+ReLU (fp16 X, scale/shift in ss)
// tile 64 rows x 64 cols, 256 threads, thread = 4 rows x 4 cols

template <int COUT, bool BNRELU, bool XHALF>
__global__ __launch_bounds__(256) void k_gemm_scale(const void* __restrict__ Xv,
                                                    const float* __restrict__ W,
                                                    const float* __restrict__ dis,
                                                    const float* __restrict__ ss,
                                                    __half* __restrict__ T, int nrows) {
  __shared__ float xs[64][132];   // row-major x tile, padded
  __shared__ float ws[128][68];   // k x col tile, padded
  const int tid = threadIdx.x;
  const int row0 = blockIdx.x * 64;
  const int c0 = blockIdx.y * 64;

  if constexpr (XHALF) {
    const __half* X = (const __half*)Xv;
#pragma unroll
    for (int i = 0; i < 4; ++i) {
      int idx = tid + i * 256;     // 0..1023 over 64 rows x 16 oct-chunks
      int r = idx >> 4, kk = idx & 15;
      int row = row0 + r;
      float f[8];
      if (row < nrows) {
        uint4 raw = *reinterpret_cast<const uint4*>(X + (size_t)row * NCH + kk * 8);
        const __half2* h2 = reinterpret_cast<const __half2*>(&raw);
#pragma unroll
        for (int j = 0; j < 4; ++j) {
          float2 t = __half22float2(h2[j]);
          f[2 * j] = t.x; f[2 * j + 1] = t.y;
        }
      } else {
#pragma unroll
        for (int j = 0; j < 8; ++j) f[j] = 0.f;
      }
      if constexpr (BNRELU) {
#pragma unroll
        for (int j = 0; j < 8; ++j) {
          int c = kk * 8 + j;
          f[j] = fmaxf(fmaf(f[j], ss[c], ss[128 + c]), 0.f);
        }
      }
#pragma unroll
      for (int j = 0; j < 8; ++j) xs[r][kk * 8 + j] = f[j];
    }
  } else {
    const float* X = (const float*)Xv;
#pragma unroll
    for (int i = 0; i < 8; ++i) {
      int idx = tid + i * 256;     // 0..2047 over 64 rows x 32 k-quads
      int r = idx >> 5, kk = idx & 31;
      int row = row0 + r;
      float4 v = make_float4(0.f, 0.f, 0.f, 0.f);
      if (row < nrows) v = *reinterpret_cast<const float4*>(X + (size_t)row * NCH + kk * 4);
      *reinterpret_cast<float4*>(&xs[r][kk * 4]) = v;
    }
  }
#pragma unroll
  for (int i = 0; i < 8; ++i) {
    int idx = tid + i * 256;       // 0..2047 over 128 k x 16 col-quads
    int k = idx >> 4, q = idx & 15;
    float4 v = *reinterpret_cast<const float4*>(W + (size_t)k * COUT + c0 + q * 4);
    *reinterpret_cast<float4*>(&ws[k][q * 4]) = v;
  }
  __syncthreads();

  const int tc = tid & 15, tr = tid >> 4;
  float4 acc0 = make_float4(0.f, 0.f, 0.f, 0.f);
  float4 acc1 = acc0, acc2 = acc0, acc3 = acc0;

#define FMA4(ACC, S, B)                                                                \
  ACC.x = fmaf(S, B.x, ACC.x); ACC.y = fmaf(S, B.y, ACC.y);                            \
  ACC.z = fmaf(S, B.z, ACC.z); ACC.w = fmaf(S, B.w, ACC.w)

#pragma unroll 8
  for (int k = 0; k < 128; k += 4) {
    float4 A0 = *reinterpret_cast<const float4*>(&xs[4 * tr + 0][k]);
    float4 A1 = *reinterpret_cast<const float4*>(&xs[4 * tr + 1][k]);
    float4 A2 = *reinterpret_cast<const float4*>(&xs[4 * tr + 2][k]);
    float4 A3 = *reinterpret_cast<const float4*>(&xs[4 * tr + 3][k]);
    float4 B0 = *reinterpret_cast<const float4*>(&ws[k + 0][4 * tc]);
    float4 B1 = *reinterpret_cast<const float4*>(&ws[k + 1][4 * tc]);
    float4 B2 = *reinterpret_cast<const float4*>(&ws[k + 2][4 * tc]);
    float4 B3 = *reinterpret_cast<const float4*>(&ws[k + 3][4 * tc]);
    FMA4(acc0, A0.x, B0); FMA4(acc0, A0.y, B1); FMA4(acc0, A0.z, B2); FMA4(acc0, A0.w, B3);
    FMA4(acc1, A1.x, B0); FMA4(acc1, A1.y, B1); FMA4(acc1, A1.z, B2); FMA4(acc1, A1.w, B3);
    FMA4(acc2, A2.x, B0); FMA4(acc2, A2.y, B1); FMA4(acc2, A2.z, B2); FMA4(acc2, A2.w, B3);
    FMA4(acc3, A3.x, B0); FMA4(acc3, A3.y, B1); FMA4(acc3, A3.z, B2); FMA4(acc3, A3.w, B3);
  }
#undef FMA4

  float4 accs[4] = {acc0, acc1, acc2, acc3};
#pragma unroll
  for (int i = 0; i < 4; ++i) {
    int row = row0 + 4 * tr + i;
    if (row < nrows) {
      float d = dis[row];
      __half2 h01 = __floats2half2_rn(accs[i].x * d, accs[i].y * d);
      __half2 h23 = __floats2half2_rn(accs[i].z * d, accs[i].w * d);
      uint2 raw;
      raw.x = *reinterpret_cast<unsigned int*>(&h01);
      raw.y = *reinterpret_cast<unsigned int*>(&h23);
      *reinterpret_cast<uint2*>(T + (size_t)row * COUT + c0 + 4 * tc) = raw;
    }
  }
}

// ---------------- pull aggregation (fp16 gather, f32 accumulate) ----------------
// wave per node; 32 lanes per row; 2 sources concurrently.
// Every __shfl at FULL-WAVE scope (shfl inside a divergent branch reads garbage
// when the source lane is exec-masked off — the round-3/4/5 bug).

__device__ __forceinline__ float4 h4_to_f4(uint2 r) {
  __half2 a = *reinterpret_cast<__half2*>(&r.x);
  __half2 b = *reinterpret_cast<__half2*>(&r.y);
  float2 fa = __half22float2(a), fb = __half22float2(b);
  return make_float4(fa.x, fa.y, fb.x, fb.y);
}

__global__ __launch_bounds__(256) void k_aggregate128(const __half* __restrict__ T,
                                                      const int* __restrict__ rowptr,
                                                      const int* __restrict__ col,
                                                      const float* __restrict__ dis,
                                                      const float* __restrict__ bias,
                                                      __half* __restrict__ OUT, int n) {
  const int lane = threadIdx.x & 63;
  const int node = blockIdx.x * 4 + (threadIdx.x >> 6);
  if (node >= n) return;
  const int sub = lane >> 5;   // which of the 2 concurrent sources
  const int cl = lane & 31;    // channel quad: 4*cl .. 4*cl+3
  const int beg = rowptr[node], end = rowptr[node + 1];

  float4 acc = make_float4(0.f, 0.f, 0.f, 0.f);
  if (sub == 0) {
    float4 v = h4_to_f4(*reinterpret_cast<const uint2*>(T + (size_t)node * 128 + cl * 4));
    acc.x += v.x; acc.y += v.y; acc.z += v.z; acc.w += v.w;
  }
  for (int e = beg; e < end;) {
    int cnt = end - e;
    if (cnt > 64) cnt = 64;
    int sl = (e + lane < end) ? col[e + lane] : 0;
    int j = 0;
    for (; j + 4 <= cnt; j += 4) {
      int s0 = __shfl(sl, j + sub);
      int s1 = __shfl(sl, j + 2 + sub);
      float4 v0 = h4_to_f4(*reinterpret_cast<const uint2*>(T + (size_t)s0 * 128 + cl * 4));
      float4 v1 = h4_to_f4(*reinterpret_cast<const uint2*>(T + (size_t)s1 * 128 + cl * 4));
      acc.x += v0.x + v1.x; acc.y += v0.y + v1.y;
      acc.z += v0.z + v1.z; acc.w += v0.w + v1.w;
    }
    if (j + 2 <= cnt) {
      int s = __shfl(sl, j + sub);          // full-wave shfl
      float4 v = h4_to_f4(*reinterpret_cast<const uint2*>(T + (size_t)s * 128 + cl * 4));
      acc.x += v.x; acc.y += v.y; acc.z += v.z; acc.w += v.w;
      j += 2;
    }
    if (j < cnt) {
      int s = __shfl(sl, j);                // full-wave shfl
      if (sub == 0) {
        float4 v = h4_to_f4(*reinterpret_cast<const uint2*>(T + (size_t)s * 128 + cl * 4));
        acc.x += v.x; acc.y += v.y; acc.z += v.z; acc.w += v.w;
      }
    }
    e += cnt;
  }
  acc.x += __shfl_xor(acc.x, 32);
  acc.y += __shfl_xor(acc.y, 32);
  acc.z += __shfl_xor(acc.z, 32);
  acc.w += __shfl_xor(acc.w, 32);
  if (sub == 0) {
    float d = dis[node];
    int c = cl * 4;
    __half2 h01 = __floats2half2_rn(fmaf(acc.x, d, bias[c]), fmaf(acc.y, d, bias[c + 1]));
    __half2 h23 = __floats2half2_rn(fmaf(acc.z, d, bias[c + 2]), fmaf(acc.w, d, bias[c + 3]));
    uint2 raw;
    raw.x = *reinterpret_cast<unsigned int*>(&h01);
    raw.y = *reinterpret_cast<unsigned int*>(&h23);
    *reinterpret_cast<uint2*>(OUT + (size_t)node * 128 + c) = raw;
  }
}

__global__ __launch_bounds__(256) void k_aggregate64(const __half* __restrict__ T,
                                                     const int* __restrict__ rowptr,
                                                     const int* __restrict__ col,
                                                     const float* __restrict__ dis,
                                                     const float* __restrict__ bias,
                                                     float* __restrict__ OUT, int n) {
  const int lane = threadIdx.x & 63;
  const int node = blockIdx.x * 4 + (threadIdx.x >> 6);
  if (node >= n) return;
  const int sub = lane >> 5;
  const int cl = lane & 31;    // channel pair 2*cl, 2*cl+1
  const int beg = rowptr[node], end = rowptr[node + 1];

  float2 acc = make_float2(0.f, 0.f);
  if (sub == 0) {
    float2 v = __half22float2(*reinterpret_cast<const __half2*>(T + (size_t)node * 64 + cl * 2));
    acc.x += v.x; acc.y += v.y;
  }
  for (int e = beg; e < end;) {
    int cnt = end - e;
    if (cnt > 64) cnt = 64;
    int sl = (e + lane < end) ? col[e + lane] : 0;
    int j = 0;
    for (; j + 4 <= cnt; j += 4) {
      int s0 = __shfl(sl, j + sub);
      int s1 = __shfl(sl, j + 2 + sub);
      float2 v0 = __half22float2(*reinterpret_cast<const __half2*>(T + (size_t)s0 * 64 + cl * 2));
      float2 v1 = __half22float2(*reinterpret_cast<const __half2*>(T + (size_t)s1 * 64 + cl * 2));
      acc.x += v0.x + v1.x; acc.y += v0.y + v1.y;
    }
    if (j + 2 <= cnt) {
      int s = __shfl(sl, j + sub);          // full-wave shfl
      float2 v = __half22float2(*reinterpret_cast<const __half2*>(T + (size_t)s * 64 + cl * 2));
      acc.x += v.x; acc.y += v.y;
      j += 2;
    }
    if (j < cnt) {
      int s = __shfl(sl, j);                // full-wave shfl
      if (sub == 0) {
        float2 v = __half22float2(*reinterpret_cast<const __half2*>(T + (size_t)s * 64 + cl * 2));
        acc.x += v.x; acc.y += v.y;
      }
    }
    e += cnt;
  }
  acc.x += __shfl_xor(acc.x, 32);
  acc.y += __shfl_xor(acc.y, 32);
  if (sub == 0) {
    float d = dis[node];
    float2 o;
    o.x = fmaf(acc.x, d, bias[cl * 2]);
    o.y = fmaf(acc.y, d, bias[cl * 2 + 1]);
    *reinterpret_cast<float2*>(OUT + (size_t)node * 64 + cl * 2) = o;
  }
}

// ---------------- BatchNorm (training-mode batch stats): partial + final ----------------

__global__ __launch_bounds__(256) void k_bn_partial(const __half* __restrict__ H,
                                                    float* __restrict__ part, int nrows) {
  const int lane = threadIdx.x & 63;   // channel pair 2*lane
  const int grp = threadIdx.x >> 6;    // 4 rows in parallel
  const __half2* H2 = reinterpret_cast<const __half2*>(H);
  float2 s = make_float2(0.f, 0.f), s2 = make_float2(0.f, 0.f);
  for (int r = blockIdx.x * 4 + grp; r < nrows; r += gridDim.x * 4) {
    float2 v = __half22float2(H2[(size_t)r * 64 + lane]);
    s.x += v.x; s.y += v.y;
    s2.x += v.x * v.x; s2.y += v.y * v.y;
  }
  __shared__ float2 ls[4][64], ls2[4][64];
  ls[grp][lane] = s;
  ls2[grp][lane] = s2;
  __syncthreads();
  if (grp == 0) {
#pragma unroll
    for (int i = 1; i < 4; ++i) {
      s.x += ls[i][lane].x; s.y += ls[i][lane].y;
      s2.x += ls2[i][lane].x; s2.y += ls2[i][lane].y;
    }
    float* po = part + (size_t)blockIdx.x * 256;
    po[2 * lane] = s.x;
    po[2 * lane + 1] = s.y;
    po[128 + 2 * lane] = s2.x;
    po[128 + 2 * lane + 1] = s2.y;
  }
}

// 1024 threads: thread (c, grp) strides over partial blocks; LDS tree over 8 groups.
__global__ __launch_bounds__(1024) void k_bn_final(const float* __restrict__ part,
                                                   const float* __restrict__ g,
                                                   const float* __restrict__ bt,
                                                   float* __restrict__ ss, int G, int nrows) {
  const int c = threadIdx.x & 127;
  const int grp = threadIdx.x >> 7;  // 0..7
  float S = 0.f, S2 = 0.f;
  for (int b = grp; b < G; b += 8) {
    S += part[(size_t)b * 256 + c];
    S2 += part[(size_t)b * 256 + 128 + c];
  }
  __shared__ float sS[8][128], sS2[8][128];
  sS[grp][c] = S;
  sS2[grp][c] = S2;
  __syncthreads();
  if (grp == 0) {
#pragma unroll
    for (int i = 1; i < 8; ++i) { S += sS[i][c]; S2 += sS2[i][c]; }
    float inv_n = 1.f / (float)nrows;
    float mean = S * inv_n;
    float var = S2 * inv_n - mean * mean;
    float sc = g[c] * rsqrtf(var + 1e-5f);
    ss[c] = sc;
    ss[128 + c] = bt[c] - mean * sc;
  }
}

// ---------------- driver ----------------

extern "C" void kernel_launch(void* const* d_in, const int* in_sizes, int n_in,
                              void* d_out, int out_size, void* d_ws, size_t ws_size,
                              hipStream_t stream) {
  const float* x  = (const float*)d_in[0];
  const int* ei   = (const int*)d_in[1];
  const float* W1 = (const float*)d_in[2];
  const float* b1 = (const float*)d_in[3];
  const float* g1 = (const float*)d_in[4];
  const float* bt1= (const float*)d_in[5];
  const float* W2 = (const float*)d_in[6];
  const float* b2 = (const float*)d_in[7];
  const float* g2 = (const float*)d_in[8];
  const float* bt2= (const float*)d_in[9];
  const float* W3 = (const float*)d_in[10];
  const float* b3 = (const float*)d_in[11];

  const int N = in_sizes[0] / NCH;
  const int E = in_sizes[1] / 2;
  const int* src = ei;
  const int* dst = ei + E;

  char* p = (char*)d_ws;
  auto take = [&](size_t bytes) -> char* {
    char* r = p;
    p += (bytes + 255) & ~(size_t)255;
    return r;
  };
  __half* bufT  = (__half*)take((size_t)N * 128 * 2);
  __half* bufH  = (__half*)take((size_t)N * 128 * 2);
  int* deg      = (int*)take((size_t)N * 4);
  float* dis    = (float*)take((size_t)N * 4);
  int* rowptr   = (int*)take((size_t)(N + 1) * 4);
  int* rptmp    = (int*)take((size_t)N * 4);
  int* rank     = (int*)take((size_t)E * 4);
  int* col      = (int*)take((size_t)E * 4);
  int* bsum     = (int*)take(1024 * 4);
  int* boff     = (int*)take(1024 * 4);
  float* part   = (float*)take((size_t)512 * 256 * 4);
  float* ss1    = (float*)take(256 * 4);
  float* ss2    = (float*)take(256 * 4);

  const int nb256 = (N + 255) / 256;
  const int NB = (N + 1023) / 1024;
  const int nb64 = (N + 63) / 64;
  const int nbAgg = (N + 3) / 4;
  const int G = 512;

  // graph structure (recomputed every call; deterministic)
  k_deg_init<<<nb256, 256, 0, stream>>>(deg, N);
  k_deg_count<<<2048, 256, 0, stream>>>(dst, deg, rank, E);
  k_dis<<<nb256, 256, 0, stream>>>(deg, dis, N);
  k_scan_block<<<NB, 1024, 0, stream>>>(deg, rptmp, bsum, N);
  k_scan_total<<<1, 1024, 0, stream>>>(bsum, boff, NB);
  k_scan_finish<<<nb256, 256, 0, stream>>>(rptmp, boff, rowptr, N, E);
  k_fill<<<2048, 256, 0, stream>>>(src, dst, rowptr, rank, col, E);

  dim3 blk(256);

  // layer 1
  k_gemm_scale<128, false, false><<<dim3(nb64, 2), blk, 0, stream>>>(x, W1, dis, nullptr, bufT, N);
  k_aggregate128<<<nbAgg, blk, 0, stream>>>(bufT, rowptr, col, dis, b1, bufH, N);
  k_bn_partial<<<G, blk, 0, stream>>>(bufH, part, N);
  k_bn_final<<<1, 1024, 0, stream>>>(part, g1, bt1, ss1, G, N);

  // layer 2 (BN1+ReLU fused into GEMM X load)
  k_gemm_scale<128, true, true><<<dim3(nb64, 2), blk, 0, stream>>>(bufH, W2, dis, ss1, bufT, N);
  k_aggregate128<<<nbAgg, blk, 0, stream>>>(bufT, rowptr, col, dis, b2, bufH, N);
  k_bn_partial<<<G, blk, 0, stream>>>(bufH, part, N);
  k_bn_final<<<1, 1024, 0, stream>>>(part, g2, bt2, ss2, G, N);

  // layer 3 (BN2+ReLU fused; aggregate straight into d_out, f32)
  k_gemm_scale<64, true, true><<<dim3(nb64, 1), blk, 0, stream>>>(bufH, W3, dis, ss2, bufT, N);
  k_aggregate64<<<nbAgg, blk, 0, stream>>>(bufT, rowptr, col, dis, b3, (float*)d_out, N);
}

// Round 8
// 453.188 us; speedup vs baseline: 2.3497x; 1.1063x over previous
//
#include <hip/hip_runtime.h>
#include <hip/hip_fp16.h>

#define NCH 128

using v8h = __attribute__((ext_vector_type(8))) _Float16;
using v4f = __attribute__((ext_vector_type(4))) float;

// ---------------- degree / CSR build ----------------

__global__ __launch_bounds__(256) void k_deg_init(int* __restrict__ deg, int n) {
  int i = blockIdx.x * 256 + threadIdx.x;
  if (i < n) deg[i] = 1;  // self-loop
}

// counts in-degree AND records each edge's arrival rank (1-based, after the self-loop init)
__global__ __launch_bounds__(256) void k_deg_count(const int* __restrict__ dst,
                                                   int* __restrict__ deg,
                                                   int* __restrict__ rank, int E) {
  int stride = gridDim.x * 256;
  for (int e = blockIdx.x * 256 + threadIdx.x; e < E; e += stride)
    rank[e] = atomicAdd(&deg[dst[e]], 1);
}

__global__ __launch_bounds__(256) void k_dis(const int* __restrict__ deg,
                                             float* __restrict__ dis, int n) {
  int i = blockIdx.x * 256 + threadIdx.x;
  if (i < n) dis[i] = rsqrtf((float)deg[i]);
}

__global__ __launch_bounds__(1024) void k_scan_block(const int* __restrict__ deg,
                                                     int* __restrict__ rptmp,
                                                     int* __restrict__ bsum, int n) {
  __shared__ int s[1024];
  int tid = threadIdx.x;
  int gid = blockIdx.x * 1024 + tid;
  int v = (gid < n) ? (deg[gid] - 1) : 0;  // in-degree excluding self-loop
  s[tid] = v;
  __syncthreads();
  for (int off = 1; off < 1024; off <<= 1) {
    int t = (tid >= off) ? s[tid - off] : 0;
    __syncthreads();
    s[tid] += t;
    __syncthreads();
  }
  if (gid < n) rptmp[gid] = s[tid] - v;  // exclusive
  if (tid == 1023) bsum[blockIdx.x] = s[1023];
}

__global__ __launch_bounds__(1024) void k_scan_total(const int* __restrict__ bsum,
                                                     int* __restrict__ boff, int nb) {
  __shared__ int s[1024];
  int t = threadIdx.x;
  int v = (t < nb) ? bsum[t] : 0;
  s[t] = v;
  __syncthreads();
  for (int off = 1; off < 1024; off <<= 1) {
    int u = (t >= off) ? s[t - off] : 0;
    __syncthreads();
    s[t] += u;
    __syncthreads();
  }
  if (t < nb) boff[t] = s[t] - v;  // exclusive
}

__global__ __launch_bounds__(256) void k_scan_finish(const int* __restrict__ rptmp,
                                                     const int* __restrict__ boff,
                                                     int* __restrict__ rowptr, int n, int E) {
  int i = blockIdx.x * 256 + threadIdx.x;
  if (i < n) rowptr[i] = rptmp[i] + boff[i >> 10];
  if (i == 0) rowptr[n] = E;
}

// atomic-free fill: position comes from rowptr + (rank-1)
__global__ __launch_bounds__(256) void k_fill(const int* __restrict__ src,
                                              const int* __restrict__ dst,
                                              const int* __restrict__ rowptr,
                                              const int* __restrict__ rank,
                                              int* __restrict__ col, int E) {
  int stride = gridDim.x * 256;
  for (int e = blockIdx.x * 256 + threadIdx.x; e < E; e += stride) {
    int p = rowptr[dst[e]] + rank[e] - 1;
    col[p] = src[e];
  }
}

// ---------------- weight prep: Wt[n][k] = fp16(W[k][n] * scale) ----------------
// scale keeps small-sigma weights (W2 ~ 5e-4) out of the fp16-subnormal range;
// 1/scale is folded into the GEMM epilogue (linear in W).

template <int COUT>
__global__ __launch_bounds__(256) void k_prep_w(const float* __restrict__ W,
                                                __half* __restrict__ Wt, float scale) {
  int t = blockIdx.x * 256 + threadIdx.x;
  if (t < 128 * COUT) {
    int k = t / COUT, n = t % COUT;
    Wt[n * 128 + k] = __float2half(W[t] * scale);
  }
}

// ---------------- MFMA GEMM: T[r][c] = fp16( dis[r]*invs * sum_k f(X[r][k])*Wt[c][k] ) ----
// No LDS: with a full-COUT block every X/Wt element is consumed exactly once,
// so fragments load straight from global (L1/L2-hot). 256 thr = 4 waves; wave w
// owns rows [blk*64 + 16w, +16); 16x16x32 MFMA, K=128 in 4 steps, COUT/16 n-tiles.
// Frag layout: A row=lane&15, k=(lane>>4)*8+j; B col=lane&15, same k;
// C col=lane&15, row=(lane>>4)*4+reg (m89-verified).

template <int COUT, bool BNRELU, bool XHALF>
__global__ __launch_bounds__(256) void k_gemm_mfma(const void* __restrict__ Xv,
                                                   const __half* __restrict__ Wt,
                                                   const float* __restrict__ dis,
                                                   const float* __restrict__ ss,
                                                   float invs,
                                                   __half* __restrict__ T, int nrows) {
  const int tid = threadIdx.x;
  const int wave = tid >> 6, lane = tid & 63;
  const int rr = lane & 15, kg = lane >> 4;
  const int arow = blockIdx.x * 64 + wave * 16 + rr;
  const int arowc = min(arow, nrows - 1);   // clamp: OOB lanes read valid memory, never store

  constexpr int NT = COUT / 16;
  v4f acc[NT] = {};

#pragma unroll
  for (int kb = 0; kb < 4; ++kb) {
    const int k0 = kb * 32 + kg * 8;
    v8h a;
    if constexpr (XHALF) {
      const __half* X = (const __half*)Xv;
      a = *reinterpret_cast<const v8h*>(X + (size_t)arowc * NCH + k0);
      if constexpr (BNRELU) {
        float4 s0 = *reinterpret_cast<const float4*>(ss + k0);
        float4 s1 = *reinterpret_cast<const float4*>(ss + k0 + 4);
        float4 h0 = *reinterpret_cast<const float4*>(ss + 128 + k0);
        float4 h1 = *reinterpret_cast<const float4*>(ss + 128 + k0 + 4);
        v8h t;
        t[0] = (_Float16)fmaxf(fmaf((float)a[0], s0.x, h0.x), 0.f);
        t[1] = (_Float16)fmaxf(fmaf((float)a[1], s0.y, h0.y), 0.f);
        t[2] = (_Float16)fmaxf(fmaf((float)a[2], s0.z, h0.z), 0.f);
        t[3] = (_Float16)fmaxf(fmaf((float)a[3], s0.w, h0.w), 0.f);
        t[4] = (_Float16)fmaxf(fmaf((float)a[4], s1.x, h1.x), 0.f);
        t[5] = (_Float16)fmaxf(fmaf((float)a[5], s1.y, h1.y), 0.f);
        t[6] = (_Float16)fmaxf(fmaf((float)a[6], s1.z, h1.z), 0.f);
        t[7] = (_Float16)fmaxf(fmaf((float)a[7], s1.w, h1.w), 0.f);
        a = t;
      }
    } else {
      const float* X = (const float*)Xv;
      float4 f0 = *reinterpret_cast<const float4*>(X + (size_t)arowc * NCH + k0);
      float4 f1 = *reinterpret_cast<const float4*>(X + (size_t)arowc * NCH + k0 + 4);
      a[0] = (_Float16)f0.x; a[1] = (_Float16)f0.y;
      a[2] = (_Float16)f0.z; a[3] = (_Float16)f0.w;
      a[4] = (_Float16)f1.x; a[5] = (_Float16)f1.y;
      a[6] = (_Float16)f1.z; a[7] = (_Float16)f1.w;
    }
#pragma unroll
    for (int nt = 0; nt < NT; ++nt) {
      v8h b = *reinterpret_cast<const v8h*>(Wt + (size_t)(nt * 16 + rr) * 128 + k0);
      acc[nt] = __builtin_amdgcn_mfma_f32_16x16x32_f16(a, b, acc[nt], 0, 0, 0);
    }
  }

  // epilogue: lane's C values live at rows kg*4+reg, col rr of each 16x16 tile
  const int crow0 = blockIdx.x * 64 + wave * 16 + kg * 4;
#pragma unroll
  for (int reg = 0; reg < 4; ++reg) {
    int r = crow0 + reg;
    if (r < nrows) {
      float dsc = dis[r] * invs;
#pragma unroll
      for (int nt = 0; nt < NT; ++nt)
        T[(size_t)r * COUT + nt * 16 + rr] = __float2half(acc[nt][reg] * dsc);
    }
  }
}

// ---------------- pull aggregation (fp16 gather, f32 accumulate) ----------------
// wave per node; 32 lanes per row; 2 sources concurrently.
// Every __shfl at FULL-WAVE scope (shfl inside a divergent branch reads garbage
// when the source lane is exec-masked off — the round-3/4/5 bug).

__device__ __forceinline__ float4 h4_to_f4(uint2 r) {
  __half2 a = *reinterpret_cast<__half2*>(&r.x);
  __half2 b = *reinterpret_cast<__half2*>(&r.y);
  float2 fa = __half22float2(a), fb = __half22float2(b);
  return make_float4(fa.x, fa.y, fb.x, fb.y);
}

__global__ __launch_bounds__(256) void k_aggregate128(const __half* __restrict__ T,
                                                      const int* __restrict__ rowptr,
                                                      const int* __restrict__ col,
                                                      const float* __restrict__ dis,
                                                      const float* __restrict__ bias,
                                                      __half* __restrict__ OUT, int n) {
  const int lane = threadIdx.x & 63;
  const int node = blockIdx.x * 4 + (threadIdx.x >> 6);
  if (node >= n) return;
  const int sub = lane >> 5;   // which of the 2 concurrent sources
  const int cl = lane & 31;    // channel quad: 4*cl .. 4*cl+3
  const int beg = rowptr[node], end = rowptr[node + 1];

  float4 acc = make_float4(0.f, 0.f, 0.f, 0.f);
  if (sub == 0) {
    float4 v = h4_to_f4(*reinterpret_cast<const uint2*>(T + (size_t)node * 128 + cl * 4));
    acc.x += v.x; acc.y += v.y; acc.z += v.z; acc.w += v.w;
  }
  for (int e = beg; e < end;) {
    int cnt = end - e;
    if (cnt > 64) cnt = 64;
    int sl = (e + lane < end) ? col[e + lane] : 0;
    int j = 0;
    for (; j + 4 <= cnt; j += 4) {
      int s0 = __shfl(sl, j + sub);
      int s1 = __shfl(sl, j + 2 + sub);
      float4 v0 = h4_to_f4(*reinterpret_cast<const uint2*>(T + (size_t)s0 * 128 + cl * 4));
      float4 v1 = h4_to_f4(*reinterpret_cast<const uint2*>(T + (size_t)s1 * 128 + cl * 4));
      acc.x += v0.x + v1.x; acc.y += v0.y + v1.y;
      acc.z += v0.z + v1.z; acc.w += v0.w + v1.w;
    }
    if (j + 2 <= cnt) {
      int s = __shfl(sl, j + sub);          // full-wave shfl
      float4 v = h4_to_f4(*reinterpret_cast<const uint2*>(T + (size_t)s * 128 + cl * 4));
      acc.x += v.x; acc.y += v.y; acc.z += v.z; acc.w += v.w;
      j += 2;
    }
    if (j < cnt) {
      int s = __shfl(sl, j);                // full-wave shfl
      if (sub == 0) {
        float4 v = h4_to_f4(*reinterpret_cast<const uint2*>(T + (size_t)s * 128 + cl * 4));
        acc.x += v.x; acc.y += v.y; acc.z += v.z; acc.w += v.w;
      }
    }
    e += cnt;
  }
  acc.x += __shfl_xor(acc.x, 32);
  acc.y += __shfl_xor(acc.y, 32);
  acc.z += __shfl_xor(acc.z, 32);
  acc.w += __shfl_xor(acc.w, 32);
  if (sub == 0) {
    float d = dis[node];
    int c = cl * 4;
    __half2 h01 = __floats2half2_rn(fmaf(acc.x, d, bias[c]), fmaf(acc.y, d, bias[c + 1]));
    __half2 h23 = __floats2half2_rn(fmaf(acc.z, d, bias[c + 2]), fmaf(acc.w, d, bias[c + 3]));
    uint2 raw;
    raw.x = *reinterpret_cast<unsigned int*>(&h01);
    raw.y = *reinterpret_cast<unsigned int*>(&h23);
    *reinterpret_cast<uint2*>(OUT + (size_t)node * 128 + c) = raw;
  }
}

__global__ __launch_bounds__(256) void k_aggregate64(const __half* __restrict__ T,
                                                     const int* __restrict__ rowptr,
                                                     const int* __restrict__ col,
                                                     const float* __restrict__ dis,
                                                     const float* __restrict__ bias,
                                                     float* __restrict__ OUT, int n) {
  const int lane = threadIdx.x & 63;
  const int node = blockIdx.x * 4 + (threadIdx.x >> 6);
  if (node >= n) return;
  const int sub = lane >> 5;
  const int cl = lane & 31;    // channel pair 2*cl, 2*cl+1
  const int beg = rowptr[node], end = rowptr[node + 1];

  float2 acc = make_float2(0.f, 0.f);
  if (sub == 0) {
    float2 v = __half22float2(*reinterpret_cast<const __half2*>(T + (size_t)node * 64 + cl * 2));
    acc.x += v.x; acc.y += v.y;
  }
  for (int e = beg; e < end;) {
    int cnt = end - e;
    if (cnt > 64) cnt = 64;
    int sl = (e + lane < end) ? col[e + lane] : 0;
    int j = 0;
    for (; j + 4 <= cnt; j += 4) {
      int s0 = __shfl(sl, j + sub);
      int s1 = __shfl(sl, j + 2 + sub);
      float2 v0 = __half22float2(*reinterpret_cast<const __half2*>(T + (size_t)s0 * 64 + cl * 2));
      float2 v1 = __half22float2(*reinterpret_cast<const __half2*>(T + (size_t)s1 * 64 + cl * 2));
      acc.x += v0.x + v1.x; acc.y += v0.y + v1.y;
    }
    if (j + 2 <= cnt) {
      int s = __shfl(sl, j + sub);          // full-wave shfl
      float2 v = __half22float2(*reinterpret_cast<const __half2*>(T + (size_t)s * 64 + cl * 2));
      acc.x += v.x; acc.y += v.y;
      j += 2;
    }
    if (j < cnt) {
      int s = __shfl(sl, j);                // full-wave shfl
      if (sub == 0) {
        float2 v = __half22float2(*reinterpret_cast<const __half2*>(T + (size_t)s * 64 + cl * 2));
        acc.x += v.x; acc.y += v.y;
      }
    }
    e += cnt;
  }
  acc.x += __shfl_xor(acc.x, 32);
  acc.y += __shfl_xor(acc.y, 32);
  if (sub == 0) {
    float d = dis[node];
    float2 o;
    o.x = fmaf(acc.x, d, bias[cl * 2]);
    o.y = fmaf(acc.y, d, bias[cl * 2 + 1]);
    *reinterpret_cast<float2*>(OUT + (size_t)node * 64 + cl * 2) = o;
  }
}

// ---------------- BatchNorm (training-mode batch stats): partial + final ----------------

__global__ __launch_bounds__(256) void k_bn_partial(const __half* __restrict__ H,
                                                    float* __restrict__ part, int nrows) {
  const int lane = threadIdx.x & 63;   // channel pair 2*lane
  const int grp = threadIdx.x >> 6;    // 4 rows in parallel
  const __half2* H2 = reinterpret_cast<const __half2*>(H);
  float2 s = make_float2(0.f, 0.f), s2 = make_float2(0.f, 0.f);
  for (int r = blockIdx.x * 4 + grp; r < nrows; r += gridDim.x * 4) {
    float2 v = __half22float2(H2[(size_t)r * 64 + lane]);
    s.x += v.x; s.y += v.y;
    s2.x += v.x * v.x; s2.y += v.y * v.y;
  }
  __shared__ float2 ls[4][64], ls2[4][64];
  ls[grp][lane] = s;
  ls2[grp][lane] = s2;
  __syncthreads();
  if (grp == 0) {
#pragma unroll
    for (int i = 1; i < 4; ++i) {
      s.x += ls[i][lane].x; s.y += ls[i][lane].y;
      s2.x += ls2[i][lane].x; s2.y += ls2[i][lane].y;
    }
    float* po = part + (size_t)blockIdx.x * 256;
    po[2 * lane] = s.x;
    po[2 * lane + 1] = s.y;
    po[128 + 2 * lane] = s2.x;
    po[128 + 2 * lane + 1] = s2.y;
  }
}

// 1024 threads: thread (c, grp) strides over partial blocks; LDS tree over 8 groups.
__global__ __launch_bounds__(1024) void k_bn_final(const float* __restrict__ part,
                                                   const float* __restrict__ g,
                                                   const float* __restrict__ bt,
                                                   float* __restrict__ ss, int G, int nrows) {
  const int c = threadIdx.x & 127;
  const int grp = threadIdx.x >> 7;  // 0..7
  float S = 0.f, S2 = 0.f;
  for (int b = grp; b < G; b += 8) {
    S += part[(size_t)b * 256 + c];
    S2 += part[(size_t)b * 256 + 128 + c];
  }
  __shared__ float sS[8][128], sS2[8][128];
  sS[grp][c] = S;
  sS2[grp][c] = S2;
  __syncthreads();
  if (grp == 0) {
#pragma unroll
    for (int i = 1; i < 8; ++i) { S += sS[i][c]; S2 += sS2[i][c]; }
    float inv_n = 1.f / (float)nrows;
    float mean = S * inv_n;
    float var = S2 * inv_n - mean * mean;
    float sc = g[c] * rsqrtf(var + 1e-5f);
    ss[c] = sc;
    ss[128 + c] = bt[c] - mean * sc;
  }
}

// ---------------- driver ----------------

extern "C" void kernel_launch(void* const* d_in, const int* in_sizes, int n_in,
                              void* d_out, int out_size, void* d_ws, size_t ws_size,
                              hipStream_t stream) {
  const float* x  = (const float*)d_in[0];
  const int* ei   = (const int*)d_in[1];
  const float* W1 = (const float*)d_in[2];
  const float* b1 = (const float*)d_in[3];
  const float* g1 = (const float*)d_in[4];
  const float* bt1= (const float*)d_in[5];
  const float* W2 = (const float*)d_in[6];
  const float* b2 = (const float*)d_in[7];
  const float* g2 = (const float*)d_in[8];
  const float* bt2= (const float*)d_in[9];
  const float* W3 = (const float*)d_in[10];
  const float* b3 = (const float*)d_in[11];

  const int N = in_sizes[0] / NCH;
  const int E = in_sizes[1] / 2;
  const int* src = ei;
  const int* dst = ei + E;

  char* p = (char*)d_ws;
  auto take = [&](size_t bytes) -> char* {
    char* r = p;
    p += (bytes + 255) & ~(size_t)255;
    return r;
  };
  __half* bufT  = (__half*)take((size_t)N * 128 * 2);
  __half* bufH  = (__half*)take((size_t)N * 128 * 2);
  int* deg      = (int*)take((size_t)N * 4);
  float* dis    = (float*)take((size_t)N * 4);
  int* rowptr   = (int*)take((size_t)(N + 1) * 4);
  int* rptmp    = (int*)take((size_t)N * 4);
  int* rank     = (int*)take((size_t)E * 4);
  int* col      = (int*)take((size_t)E * 4);
  int* bsum     = (int*)take(1024 * 4);
  int* boff     = (int*)take(1024 * 4);
  float* part   = (float*)take((size_t)512 * 256 * 4);
  float* ss1    = (float*)take(256 * 4);
  float* ss2    = (float*)take(256 * 4);
  __half* Wt1   = (__half*)take((size_t)128 * 128 * 2);
  __half* Wt2   = (__half*)take((size_t)128 * 128 * 2);
  __half* Wt3   = (__half*)take((size_t)64 * 128 * 2);

  const int nb256 = (N + 255) / 256;
  const int NB = (N + 1023) / 1024;
  const int nb64 = (N + 63) / 64;
  const int nbAgg = (N + 3) / 4;
  const int G = 512;

  const float S1 = 8.f, S2 = 512.f, S3 = 8.f;  // fp16 anti-subnormal weight scales

  // weight prep (independent of graph build)
  k_prep_w<128><<<64, 256, 0, stream>>>(W1, Wt1, S1);
  k_prep_w<128><<<64, 256, 0, stream>>>(W2, Wt2, S2);
  k_prep_w<64><<<32, 256, 0, stream>>>(W3, Wt3, S3);

  // graph structure (recomputed every call; deterministic)
  k_deg_init<<<nb256, 256, 0, stream>>>(deg, N);
  k_deg_count<<<2048, 256, 0, stream>>>(dst, deg, rank, E);
  k_dis<<<nb256, 256, 0, stream>>>(deg, dis, N);
  k_scan_block<<<NB, 1024, 0, stream>>>(deg, rptmp, bsum, N);
  k_scan_total<<<1, 1024, 0, stream>>>(bsum, boff, NB);
  k_scan_finish<<<nb256, 256, 0, stream>>>(rptmp, boff, rowptr, N, E);
  k_fill<<<2048, 256, 0, stream>>>(src, dst, rowptr, rank, col, E);

  dim3 blk(256);

  // layer 1
  k_gemm_mfma<128, false, false><<<nb64, blk, 0, stream>>>(x, Wt1, dis, nullptr, 1.f / S1, bufT, N);
  k_aggregate128<<<nbAgg, blk, 0, stream>>>(bufT, rowptr, col, dis, b1, bufH, N);
  k_bn_partial<<<G, blk, 0, stream>>>(bufH, part, N);
  k_bn_final<<<1, 1024, 0, stream>>>(part, g1, bt1, ss1, G, N);

  // layer 2 (BN1+ReLU fused into GEMM A-fragment load)
  k_gemm_mfma<128, true, true><<<nb64, blk, 0, stream>>>(bufH, Wt2, dis, ss1, 1.f / S2, bufT, N);
  k_aggregate128<<<nbAgg, blk, 0, stream>>>(bufT, rowptr, col, dis, b2, bufH, N);
  k_bn_partial<<<G, blk, 0, stream>>>(bufH, part, N);
  k_bn_final<<<1, 1024, 0, stream>>>(part, g2, bt2, ss2, G, N);

  // layer 3 (BN2+ReLU fused; aggregate straight into d_out, f32)
  k_gemm_mfma<64, true, true><<<nb64, blk, 0, stream>>>(bufH, Wt3, dis, ss2, 1.f / S3, bufT, N);
  k_aggregate64<<<nbAgg, blk, 0, stream>>>(bufT, rowptr, col, dis, b3, (float*)d_out, N);
}

// Round 9
// 411.805 us; speedup vs baseline: 2.5858x; 1.1005x over previous
//
#include <hip/hip_runtime.h>
#include <hip/hip_fp16.h>

#define NCH 128
#define BSH 9                 // bucket shift: 512 nodes per bucket
#define NBLK 256              // edge-slice blocks for bucket count/scatter

using v8h = __attribute__((ext_vector_type(8))) _Float16;
using v4f = __attribute__((ext_vector_type(4))) float;

// ---------------- bucketed counting-sort CSR build ----------------
// Replaces global-atomic histogram + scatter fill (scattered 4B atomics are
// ~write-through at 64B granularity -> 56MB HBM writes, 0.9 TB/s; round-8 PMC).
// All contention now lives in LDS; global traffic is coalesced or L2-local.

// P1: per-(bucket, block) edge counts. Block b handles contiguous slice.
__global__ __launch_bounds__(256) void k_bcount(const int* __restrict__ dst,
                                                int* __restrict__ cnt,
                                                int E, int epb, int nbk) {
  extern __shared__ int lc[];   // nbk
  for (int i = threadIdx.x; i < nbk; i += 256) lc[i] = 0;
  __syncthreads();
  const int b = blockIdx.x;
  const int e0 = b * epb, e1 = min(E, e0 + epb);
  for (int e = e0 + threadIdx.x; e < e1; e += 256)
    atomicAdd(&lc[dst[e] >> BSH], 1);
  __syncthreads();
  for (int i = threadIdx.x; i < nbk; i += 256)
    cnt[i * NBLK + b] = lc[i];
}

// generic scan chain (Hillis-Steele, 1024-wide blocks)
__global__ __launch_bounds__(1024) void k_scan_blockg(const int* __restrict__ in,
                                                      int* __restrict__ rptmp,
                                                      int* __restrict__ bsum, int n) {
  __shared__ int s[1024];
  int tid = threadIdx.x;
  int gid = blockIdx.x * 1024 + tid;
  int v = (gid < n) ? in[gid] : 0;
  s[tid] = v;
  __syncthreads();
  for (int off = 1; off < 1024; off <<= 1) {
    int t = (tid >= off) ? s[tid - off] : 0;
    __syncthreads();
    s[tid] += t;
    __syncthreads();
  }
  if (gid < n) rptmp[gid] = s[tid] - v;  // exclusive
  if (tid == 1023) bsum[blockIdx.x] = s[1023];
}

__global__ __launch_bounds__(1024) void k_scan_total(const int* __restrict__ bsum,
                                                     int* __restrict__ boff, int nb) {
  __shared__ int s[1024];
  int t = threadIdx.x;
  int v = (t < nb) ? bsum[t] : 0;
  s[t] = v;
  __syncthreads();
  for (int off = 1; off < 1024; off <<= 1) {
    int u = (t >= off) ? s[t - off] : 0;
    __syncthreads();
    s[t] += u;
    __syncthreads();
  }
  if (t < nb) boff[t] = s[t] - v;  // exclusive
}

__global__ __launch_bounds__(256) void k_scan_fing(const int* __restrict__ rptmp,
                                                   const int* __restrict__ boff,
                                                   int* __restrict__ out, int n) {
  int i = blockIdx.x * 256 + threadIdx.x;
  if (i < n) out[i] = rptmp[i] + boff[i >> 10];
}

// P2: scatter edges into bucket-sorted ebuf (pairs src,dst).
__global__ __launch_bounds__(256) void k_bscatter(const int* __restrict__ src,
                                                  const int* __restrict__ dst,
                                                  const int* __restrict__ gbase,
                                                  uint2* __restrict__ ebuf,
                                                  int E, int epb, int nbk) {
  extern __shared__ int lc[];   // nbk
  for (int i = threadIdx.x; i < nbk; i += 256) lc[i] = 0;
  __syncthreads();
  const int b = blockIdx.x;
  const int e0 = b * epb, e1 = min(E, e0 + epb);
  for (int e = e0 + threadIdx.x; e < e1; e += 256) {
    int d = dst[e];
    int bk = d >> BSH;
    int r = atomicAdd(&lc[bk], 1);
    int pos = gbase[bk * NBLK + b] + r;
    ebuf[pos] = make_uint2((unsigned)src[e], (unsigned)d);
  }
}

// P3: per-bucket CSR finalize: rowptr, dis, col. One block per bucket.
__global__ __launch_bounds__(256) void k_bcsr(const uint2* __restrict__ ebuf,
                                              const int* __restrict__ gbase,
                                              int* __restrict__ rowptr,
                                              float* __restrict__ dis,
                                              int* __restrict__ col,
                                              int N, int E, int nbk) {
  __shared__ int ldeg[512], s[512], lrp[512], lfill[512];
  const int b = blockIdx.x;
  const int t = threadIdx.x;
  const int node0 = b << BSH;
  const int ebeg = gbase[b * NBLK];
  const int eend = (b == nbk - 1) ? E : gbase[(b + 1) * NBLK];

  ldeg[t] = 0; ldeg[t + 256] = 0;
  lfill[t] = 0; lfill[t + 256] = 0;
  __syncthreads();
  for (int i = ebeg + t; i < eend; i += 256)
    atomicAdd(&ldeg[ebuf[i].y - node0], 1);
  __syncthreads();
  // inclusive scan of 512 entries with 256 threads
  int v0 = ldeg[t], v1 = ldeg[t + 256];
  s[t] = v0; s[t + 256] = v1;
  __syncthreads();
  for (int off = 1; off < 512; off <<= 1) {
    int a0 = (t >= off) ? s[t - off] : 0;
    int a1 = (t + 256 >= off) ? s[t + 256 - off] : 0;
    __syncthreads();
    s[t] += a0; s[t + 256] += a1;
    __syncthreads();
  }
  lrp[t] = s[t] - v0;              // exclusive
  lrp[t + 256] = s[t + 256] - v1;
  __syncthreads();
  // rowptr + dis (deg includes the self-loop: +1)
#pragma unroll
  for (int q = 0; q < 2; ++q) {
    int i = t + q * 256;
    int node = node0 + i;
    if (node < N) {
      rowptr[node] = ebeg + lrp[i];
      dis[node] = rsqrtf((float)(ldeg[i] + 1));
    }
  }
  if (b == nbk - 1 && t == 0) rowptr[N] = E;
  // fill col (scatter confined to this bucket's region)
  for (int i = ebeg + t; i < eend; i += 256) {
    uint2 p = ebuf[i];
    int off = p.y - node0;
    int r = atomicAdd(&lfill[off], 1);
    col[ebeg + lrp[off] + r] = (int)p.x;
  }
}

// ---------------- weight prep: Wt[n][k] = fp16(W[k][n] * scale) ----------------
// scale keeps small-sigma weights (W2 ~ 5e-4) out of the fp16-subnormal range;
// 1/scale is folded into the GEMM epilogue (linear in W).

template <int COUT>
__global__ __launch_bounds__(256) void k_prep_w(const float* __restrict__ W,
                                                __half* __restrict__ Wt, float scale) {
  int t = blockIdx.x * 256 + threadIdx.x;
  if (t < 128 * COUT) {
    int k = t / COUT, n = t % COUT;
    Wt[n * 128 + k] = __float2half(W[t] * scale);
  }
}

// ---------------- MFMA GEMM: T[r][c] = fp16( dis[r]*invs * sum_k f(X[r][k])*Wt[c][k] ) ----
// No LDS: with a full-COUT block every X/Wt element is consumed exactly once,
// so fragments load straight from global (L1/L2-hot). 256 thr = 4 waves; wave w
// owns rows [blk*64 + 16w, +16); 16x16x32 MFMA, K=128 in 4 steps, COUT/16 n-tiles.

template <int COUT, bool BNRELU, bool XHALF>
__global__ __launch_bounds__(256) void k_gemm_mfma(const void* __restrict__ Xv,
                                                   const __half* __restrict__ Wt,
                                                   const float* __restrict__ dis,
                                                   const float* __restrict__ ss,
                                                   float invs,
                                                   __half* __restrict__ T, int nrows) {
  const int tid = threadIdx.x;
  const int wave = tid >> 6, lane = tid & 63;
  const int rr = lane & 15, kg = lane >> 4;
  const int arow = blockIdx.x * 64 + wave * 16 + rr;
  const int arowc = min(arow, nrows - 1);   // clamp: OOB lanes read valid memory, never store

  constexpr int NT = COUT / 16;
  v4f acc[NT] = {};

#pragma unroll
  for (int kb = 0; kb < 4; ++kb) {
    const int k0 = kb * 32 + kg * 8;
    v8h a;
    if constexpr (XHALF) {
      const __half* X = (const __half*)Xv;
      a = *reinterpret_cast<const v8h*>(X + (size_t)arowc * NCH + k0);
      if constexpr (BNRELU) {
        float4 s0 = *reinterpret_cast<const float4*>(ss + k0);
        float4 s1 = *reinterpret_cast<const float4*>(ss + k0 + 4);
        float4 h0 = *reinterpret_cast<const float4*>(ss + 128 + k0);
        float4 h1 = *reinterpret_cast<const float4*>(ss + 128 + k0 + 4);
        v8h t;
        t[0] = (_Float16)fmaxf(fmaf((float)a[0], s0.x, h0.x), 0.f);
        t[1] = (_Float16)fmaxf(fmaf((float)a[1], s0.y, h0.y), 0.f);
        t[2] = (_Float16)fmaxf(fmaf((float)a[2], s0.z, h0.z), 0.f);
        t[3] = (_Float16)fmaxf(fmaf((float)a[3], s0.w, h0.w), 0.f);
        t[4] = (_Float16)fmaxf(fmaf((float)a[4], s1.x, h1.x), 0.f);
        t[5] = (_Float16)fmaxf(fmaf((float)a[5], s1.y, h1.y), 0.f);
        t[6] = (_Float16)fmaxf(fmaf((float)a[6], s1.z, h1.z), 0.f);
        t[7] = (_Float16)fmaxf(fmaf((float)a[7], s1.w, h1.w), 0.f);
        a = t;
      }
    } else {
      const float* X = (const float*)Xv;
      float4 f0 = *reinterpret_cast<const float4*>(X + (size_t)arowc * NCH + k0);
      float4 f1 = *reinterpret_cast<const float4*>(X + (size_t)arowc * NCH + k0 + 4);
      a[0] = (_Float16)f0.x; a[1] = (_Float16)f0.y;
      a[2] = (_Float16)f0.z; a[3] = (_Float16)f0.w;
      a[4] = (_Float16)f1.x; a[5] = (_Float16)f1.y;
      a[6] = (_Float16)f1.z; a[7] = (_Float16)f1.w;
    }
#pragma unroll
    for (int nt = 0; nt < NT; ++nt) {
      v8h b = *reinterpret_cast<const v8h*>(Wt + (size_t)(nt * 16 + rr) * 128 + k0);
      acc[nt] = __builtin_amdgcn_mfma_f32_16x16x32_f16(a, b, acc[nt], 0, 0, 0);
    }
  }

  const int crow0 = blockIdx.x * 64 + wave * 16 + kg * 4;
#pragma unroll
  for (int reg = 0; reg < 4; ++reg) {
    int r = crow0 + reg;
    if (r < nrows) {
      float dsc = dis[r] * invs;
#pragma unroll
      for (int nt = 0; nt < NT; ++nt)
        T[(size_t)r * COUT + nt * 16 + rr] = __float2half(acc[nt][reg] * dsc);
    }
  }
}

// ---------------- pull aggregation (fp16 gather, f32 accumulate) ----------------
// wave per node; 32 lanes per row; 2 sources concurrently.
// Every __shfl at FULL-WAVE scope (shfl inside a divergent branch reads garbage
// when the source lane is exec-masked off — the round-3/4/5 bug).

__device__ __forceinline__ float4 h4_to_f4(uint2 r) {
  __half2 a = *reinterpret_cast<__half2*>(&r.x);
  __half2 b = *reinterpret_cast<__half2*>(&r.y);
  float2 fa = __half22float2(a), fb = __half22float2(b);
  return make_float4(fa.x, fa.y, fb.x, fb.y);
}

__global__ __launch_bounds__(256) void k_aggregate128(const __half* __restrict__ T,
                                                      const int* __restrict__ rowptr,
                                                      const int* __restrict__ col,
                                                      const float* __restrict__ dis,
                                                      const float* __restrict__ bias,
                                                      __half* __restrict__ OUT, int n) {
  const int lane = threadIdx.x & 63;
  const int node = blockIdx.x * 4 + (threadIdx.x >> 6);
  if (node >= n) return;
  const int sub = lane >> 5;   // which of the 2 concurrent sources
  const int cl = lane & 31;    // channel quad: 4*cl .. 4*cl+3
  const int beg = rowptr[node], end = rowptr[node + 1];

  float4 acc = make_float4(0.f, 0.f, 0.f, 0.f);
  if (sub == 0) {
    float4 v = h4_to_f4(*reinterpret_cast<const uint2*>(T + (size_t)node * 128 + cl * 4));
    acc.x += v.x; acc.y += v.y; acc.z += v.z; acc.w += v.w;
  }
  for (int e = beg; e < end;) {
    int cnt = end - e;
    if (cnt > 64) cnt = 64;
    int sl = (e + lane < end) ? col[e + lane] : 0;
    int j = 0;
    for (; j + 4 <= cnt; j += 4) {
      int s0 = __shfl(sl, j + sub);
      int s1 = __shfl(sl, j + 2 + sub);
      float4 v0 = h4_to_f4(*reinterpret_cast<const uint2*>(T + (size_t)s0 * 128 + cl * 4));
      float4 v1 = h4_to_f4(*reinterpret_cast<const uint2*>(T + (size_t)s1 * 128 + cl * 4));
      acc.x += v0.x + v1.x; acc.y += v0.y + v1.y;
      acc.z += v0.z + v1.z; acc.w += v0.w + v1.w;
    }
    if (j + 2 <= cnt) {
      int s = __shfl(sl, j + sub);          // full-wave shfl
      float4 v = h4_to_f4(*reinterpret_cast<const uint2*>(T + (size_t)s * 128 + cl * 4));
      acc.x += v.x; acc.y += v.y; acc.z += v.z; acc.w += v.w;
      j += 2;
    }
    if (j < cnt) {
      int s = __shfl(sl, j);                // full-wave shfl
      if (sub == 0) {
        float4 v = h4_to_f4(*reinterpret_cast<const uint2*>(T + (size_t)s * 128 + cl * 4));
        acc.x += v.x; acc.y += v.y; acc.z += v.z; acc.w += v.w;
      }
    }
    e += cnt;
  }
  acc.x += __shfl_xor(acc.x, 32);
  acc.y += __shfl_xor(acc.y, 32);
  acc.z += __shfl_xor(acc.z, 32);
  acc.w += __shfl_xor(acc.w, 32);
  if (sub == 0) {
    float d = dis[node];
    int c = cl * 4;
    __half2 h01 = __floats2half2_rn(fmaf(acc.x, d, bias[c]), fmaf(acc.y, d, bias[c + 1]));
    __half2 h23 = __floats2half2_rn(fmaf(acc.z, d, bias[c + 2]), fmaf(acc.w, d, bias[c + 3]));
    uint2 raw;
    raw.x = *reinterpret_cast<unsigned int*>(&h01);
    raw.y = *reinterpret_cast<unsigned int*>(&h23);
    *reinterpret_cast<uint2*>(OUT + (size_t)node * 128 + c) = raw;
  }
}

__global__ __launch_bounds__(256) void k_aggregate64(const __half* __restrict__ T,
                                                     const int* __restrict__ rowptr,
                                                     const int* __restrict__ col,
                                                     const float* __restrict__ dis,
                                                     const float* __restrict__ bias,
                                                     float* __restrict__ OUT, int n) {
  const int lane = threadIdx.x & 63;
  const int node = blockIdx.x * 4 + (threadIdx.x >> 6);
  if (node >= n) return;
  const int sub = lane >> 5;
  const int cl = lane & 31;    // channel pair 2*cl, 2*cl+1
  const int beg = rowptr[node], end = rowptr[node + 1];

  float2 acc = make_float2(0.f, 0.f);
  if (sub == 0) {
    float2 v = __half22float2(*reinterpret_cast<const __half2*>(T + (size_t)node * 64 + cl * 2));
    acc.x += v.x; acc.y += v.y;
  }
  for (int e = beg; e < end;) {
    int cnt = end - e;
    if (cnt > 64) cnt = 64;
    int sl = (e + lane < end) ? col[e + lane] : 0;
    int j = 0;
    for (; j + 4 <= cnt; j += 4) {
      int s0 = __shfl(sl, j + sub);
      int s1 = __shfl(sl, j + 2 + sub);
      float2 v0 = __half22float2(*reinterpret_cast<const __half2*>(T + (size_t)s0 * 64 + cl * 2));
      float2 v1 = __half22float2(*reinterpret_cast<const __half2*>(T + (size_t)s1 * 64 + cl * 2));
      acc.x += v0.x + v1.x; acc.y += v0.y + v1.y;
    }
    if (j + 2 <= cnt) {
      int s = __shfl(sl, j + sub);          // full-wave shfl
      float2 v = __half22float2(*reinterpret_cast<const __half2*>(T + (size_t)s * 64 + cl * 2));
      acc.x += v.x; acc.y += v.y;
      j += 2;
    }
    if (j < cnt) {
      int s = __shfl(sl, j);                // full-wave shfl
      if (sub == 0) {
        float2 v = __half22float2(*reinterpret_cast<const __half2*>(T + (size_t)s * 64 + cl * 2));
        acc.x += v.x; acc.y += v.y;
      }
    }
    e += cnt;
  }
  acc.x += __shfl_xor(acc.x, 32);
  acc.y += __shfl_xor(acc.y, 32);
  if (sub == 0) {
    float d = dis[node];
    float2 o;
    o.x = fmaf(acc.x, d, bias[cl * 2]);
    o.y = fmaf(acc.y, d, bias[cl * 2 + 1]);
    *reinterpret_cast<float2*>(OUT + (size_t)node * 64 + cl * 2) = o;
  }
}

// ---------------- BatchNorm (training-mode batch stats): partial + final ----------------

__global__ __launch_bounds__(256) void k_bn_partial(const __half* __restrict__ H,
                                                    float* __restrict__ part, int nrows) {
  const int lane = threadIdx.x & 63;   // channel pair 2*lane
  const int grp = threadIdx.x >> 6;    // 4 rows in parallel
  const __half2* H2 = reinterpret_cast<const __half2*>(H);
  float2 s = make_float2(0.f, 0.f), s2 = make_float2(0.f, 0.f);
  for (int r = blockIdx.x * 4 + grp; r < nrows; r += gridDim.x * 4) {
    float2 v = __half22float2(H2[(size_t)r * 64 + lane]);
    s.x += v.x; s.y += v.y;
    s2.x += v.x * v.x; s2.y += v.y * v.y;
  }
  __shared__ float2 ls[4][64], ls2[4][64];
  ls[grp][lane] = s;
  ls2[grp][lane] = s2;
  __syncthreads();
  if (grp == 0) {
#pragma unroll
    for (int i = 1; i < 4; ++i) {
      s.x += ls[i][lane].x; s.y += ls[i][lane].y;
      s2.x += ls2[i][lane].x; s2.y += ls2[i][lane].y;
    }
    float* po = part + (size_t)blockIdx.x * 256;
    po[2 * lane] = s.x;
    po[2 * lane + 1] = s.y;
    po[128 + 2 * lane] = s2.x;
    po[128 + 2 * lane + 1] = s2.y;
  }
}

// 1024 threads: thread (c, grp) strides over partial blocks; LDS tree over 8 groups.
__global__ __launch_bounds__(1024) void k_bn_final(const float* __restrict__ part,
                                                   const float* __restrict__ g,
                                                   const float* __restrict__ bt,
                                                   float* __restrict__ ss, int G, int nrows) {
  const int c = threadIdx.x & 127;
  const int grp = threadIdx.x >> 7;  // 0..7
  float S = 0.f, S2 = 0.f;
  for (int b = grp; b < G; b += 8) {
    S += part[(size_t)b * 256 + c];
    S2 += part[(size_t)b * 256 + 128 + c];
  }
  __shared__ float sS[8][128], sS2[8][128];
  sS[grp][c] = S;
  sS2[grp][c] = S2;
  __syncthreads();
  if (grp == 0) {
#pragma unroll
    for (int i = 1; i < 8; ++i) { S += sS[i][c]; S2 += sS2[i][c]; }
    float inv_n = 1.f / (float)nrows;
    float mean = S * inv_n;
    float var = S2 * inv_n - mean * mean;
    float sc = g[c] * rsqrtf(var + 1e-5f);
    ss[c] = sc;
    ss[128 + c] = bt[c] - mean * sc;
  }
}

// ---------------- driver ----------------

extern "C" void kernel_launch(void* const* d_in, const int* in_sizes, int n_in,
                              void* d_out, int out_size, void* d_ws, size_t ws_size,
                              hipStream_t stream) {
  const float* x  = (const float*)d_in[0];
  const int* ei   = (const int*)d_in[1];
  const float* W1 = (const float*)d_in[2];
  const float* b1 = (const float*)d_in[3];
  const float* g1 = (const float*)d_in[4];
  const float* bt1= (const float*)d_in[5];
  const float* W2 = (const float*)d_in[6];
  const float* b2 = (const float*)d_in[7];
  const float* g2 = (const float*)d_in[8];
  const float* bt2= (const float*)d_in[9];
  const float* W3 = (const float*)d_in[10];
  const float* b3 = (const float*)d_in[11];

  const int N = in_sizes[0] / NCH;
  const int E = in_sizes[1] / 2;
  const int* src = ei;
  const int* dst = ei + E;

  const int NBK = (N + (1 << BSH) - 1) >> BSH;   // buckets (196 for N=100k)
  const int CNTN = NBK * NBLK;                   // cnt entries (50176)
  const int EPB = (E + NBLK - 1) / NBLK;         // edges per slice block

  char* p = (char*)d_ws;
  auto take = [&](size_t bytes) -> char* {
    char* r = p;
    p += (bytes + 255) & ~(size_t)255;
    return r;
  };
  __half* bufT  = (__half*)take((size_t)N * 128 * 2);
  __half* bufH  = (__half*)take((size_t)N * 128 * 2);
  float* dis    = (float*)take((size_t)N * 4);
  int* rowptr   = (int*)take((size_t)(N + 1) * 4);
  int* col      = (int*)take((size_t)E * 4);
  uint2* ebuf   = (uint2*)take((size_t)E * 8);
  int* cnt      = (int*)take((size_t)CNTN * 4);
  int* gbase    = (int*)take((size_t)CNTN * 4);
  int* rptmp    = (int*)take((size_t)CNTN * 4);
  int* bsum     = (int*)take(1024 * 4);
  int* boff     = (int*)take(1024 * 4);
  float* part   = (float*)take((size_t)512 * 256 * 4);
  float* ss1    = (float*)take(256 * 4);
  float* ss2    = (float*)take(256 * 4);
  __half* Wt1   = (__half*)take((size_t)128 * 128 * 2);
  __half* Wt2   = (__half*)take((size_t)128 * 128 * 2);
  __half* Wt3   = (__half*)take((size_t)64 * 128 * 2);

  const int nb64 = (N + 63) / 64;
  const int nbAgg = (N + 3) / 4;
  const int G = 512;
  const int NSC = (CNTN + 1023) / 1024;
  const size_t ldsB = (size_t)NBK * 4;

  const float S1 = 8.f, S2 = 512.f, S3 = 8.f;  // fp16 anti-subnormal weight scales

  // weight prep (independent of graph build)
  k_prep_w<128><<<64, 256, 0, stream>>>(W1, Wt1, S1);
  k_prep_w<128><<<64, 256, 0, stream>>>(W2, Wt2, S2);
  k_prep_w<64><<<32, 256, 0, stream>>>(W3, Wt3, S3);

  // CSR build via bucketed counting sort (recomputed every call; deterministic)
  k_bcount<<<NBLK, 256, ldsB, stream>>>(dst, cnt, E, EPB, NBK);
  k_scan_blockg<<<NSC, 1024, 0, stream>>>(cnt, rptmp, bsum, CNTN);
  k_scan_total<<<1, 1024, 0, stream>>>(bsum, boff, NSC);
  k_scan_fing<<<(CNTN + 255) / 256, 256, 0, stream>>>(rptmp, boff, gbase, CNTN);
  k_bscatter<<<NBLK, 256, ldsB, stream>>>(src, dst, gbase, ebuf, E, EPB, NBK);
  k_bcsr<<<NBK, 256, 0, stream>>>(ebuf, gbase, rowptr, dis, col, N, E, NBK);

  dim3 blk(256);

  // layer 1
  k_gemm_mfma<128, false, false><<<nb64, blk, 0, stream>>>(x, Wt1, dis, nullptr, 1.f / S1, bufT, N);
  k_aggregate128<<<nbAgg, blk, 0, stream>>>(bufT, rowptr, col, dis, b1, bufH, N);
  k_bn_partial<<<G, blk, 0, stream>>>(bufH, part, N);
  k_bn_final<<<1, 1024, 0, stream>>>(part, g1, bt1, ss1, G, N);

  // layer 2 (BN1+ReLU fused into GEMM A-fragment load)
  k_gemm_mfma<128, true, true><<<nb64, blk, 0, stream>>>(bufH, Wt2, dis, ss1, 1.f / S2, bufT, N);
  k_aggregate128<<<nbAgg, blk, 0, stream>>>(bufT, rowptr, col, dis, b2, bufH, N);
  k_bn_partial<<<G, blk, 0, stream>>>(bufH, part, N);
  k_bn_final<<<1, 1024, 0, stream>>>(part, g2, bt2, ss2, G, N);

  // layer 3 (BN2+ReLU fused; aggregate straight into d_out, f32)
  k_gemm_mfma<64, true, true><<<nb64, blk, 0, stream>>>(bufH, Wt3, dis, ss2, 1.f / S3, bufT, N);
  k_aggregate64<<<nbAgg, blk, 0, stream>>>(bufT, rowptr, col, dis, b3, (float*)d_out, N);
}

// Round 10
// 400.258 us; speedup vs baseline: 2.6604x; 1.0288x over previous
//
#include <hip/hip_runtime.h>
#include <hip/hip_fp16.h>

#define NCH 128
#define BSH 9                 // bucket shift: 512 nodes per bucket
#define NBLK 256              // edge-slice blocks for bucket count/scatter

using v8h = __attribute__((ext_vector_type(8))) _Float16;
using v4f = __attribute__((ext_vector_type(4))) float;

// ---------------- bucketed counting-sort CSR build ----------------

__global__ __launch_bounds__(256) void k_bcount(const int* __restrict__ dst,
                                                int* __restrict__ cnt,
                                                int E, int epb, int nbk) {
  extern __shared__ int lc[];   // nbk
  for (int i = threadIdx.x; i < nbk; i += 256) lc[i] = 0;
  __syncthreads();
  const int b = blockIdx.x;
  const int e0 = b * epb, e1 = min(E, e0 + epb);
  for (int e = e0 + threadIdx.x; e < e1; e += 256)
    atomicAdd(&lc[dst[e] >> BSH], 1);
  __syncthreads();
  for (int i = threadIdx.x; i < nbk; i += 256)
    cnt[i * NBLK + b] = lc[i];
}

__global__ __launch_bounds__(1024) void k_scan_blockg(const int* __restrict__ in,
                                                      int* __restrict__ rptmp,
                                                      int* __restrict__ bsum, int n) {
  __shared__ int s[1024];
  int tid = threadIdx.x;
  int gid = blockIdx.x * 1024 + tid;
  int v = (gid < n) ? in[gid] : 0;
  s[tid] = v;
  __syncthreads();
  for (int off = 1; off < 1024; off <<= 1) {
    int t = (tid >= off) ? s[tid - off] : 0;
    __syncthreads();
    s[tid] += t;
    __syncthreads();
  }
  if (gid < n) rptmp[gid] = s[tid] - v;  // exclusive
  if (tid == 1023) bsum[blockIdx.x] = s[1023];
}

__global__ __launch_bounds__(1024) void k_scan_total(const int* __restrict__ bsum,
                                                     int* __restrict__ boff, int nb) {
  __shared__ int s[1024];
  int t = threadIdx.x;
  int v = (t < nb) ? bsum[t] : 0;
  s[t] = v;
  __syncthreads();
  for (int off = 1; off < 1024; off <<= 1) {
    int u = (t >= off) ? s[t - off] : 0;
    __syncthreads();
    s[t] += u;
    __syncthreads();
  }
  if (t < nb) boff[t] = s[t] - v;  // exclusive
}

__global__ __launch_bounds__(256) void k_scan_fing(const int* __restrict__ rptmp,
                                                   const int* __restrict__ boff,
                                                   int* __restrict__ out, int n) {
  int i = blockIdx.x * 256 + threadIdx.x;
  if (i < n) out[i] = rptmp[i] + boff[i >> 10];
}

__global__ __launch_bounds__(256) void k_bscatter(const int* __restrict__ src,
                                                  const int* __restrict__ dst,
                                                  const int* __restrict__ gbase,
                                                  uint2* __restrict__ ebuf,
                                                  int E, int epb, int nbk) {
  extern __shared__ int lc[];   // nbk
  for (int i = threadIdx.x; i < nbk; i += 256) lc[i] = 0;
  __syncthreads();
  const int b = blockIdx.x;
  const int e0 = b * epb, e1 = min(E, e0 + epb);
  for (int e = e0 + threadIdx.x; e < e1; e += 256) {
    int d = dst[e];
    int bk = d >> BSH;
    int r = atomicAdd(&lc[bk], 1);
    int pos = gbase[bk * NBLK + b] + r;
    ebuf[pos] = make_uint2((unsigned)src[e], (unsigned)d);
  }
}

__global__ __launch_bounds__(256) void k_bcsr(const uint2* __restrict__ ebuf,
                                              const int* __restrict__ gbase,
                                              int* __restrict__ rowptr,
                                              float* __restrict__ dis,
                                              int* __restrict__ col,
                                              int N, int E, int nbk) {
  __shared__ int ldeg[512], s[512], lrp[512], lfill[512];
  const int b = blockIdx.x;
  const int t = threadIdx.x;
  const int node0 = b << BSH;
  const int ebeg = gbase[b * NBLK];
  const int eend = (b == nbk - 1) ? E : gbase[(b + 1) * NBLK];

  ldeg[t] = 0; ldeg[t + 256] = 0;
  lfill[t] = 0; lfill[t + 256] = 0;
  __syncthreads();
  for (int i = ebeg + t; i < eend; i += 256)
    atomicAdd(&ldeg[ebuf[i].y - node0], 1);
  __syncthreads();
  int v0 = ldeg[t], v1 = ldeg[t + 256];
  s[t] = v0; s[t + 256] = v1;
  __syncthreads();
  for (int off = 1; off < 512; off <<= 1) {
    int a0 = (t >= off) ? s[t - off] : 0;
    int a1 = (t + 256 >= off) ? s[t + 256 - off] : 0;
    __syncthreads();
    s[t] += a0; s[t + 256] += a1;
    __syncthreads();
  }
  lrp[t] = s[t] - v0;              // exclusive
  lrp[t + 256] = s[t + 256] - v1;
  __syncthreads();
#pragma unroll
  for (int q = 0; q < 2; ++q) {
    int i = t + q * 256;
    int node = node0 + i;
    if (node < N) {
      rowptr[node] = ebeg + lrp[i];
      dis[node] = rsqrtf((float)(ldeg[i] + 1));
    }
  }
  if (b == nbk - 1 && t == 0) rowptr[N] = E;
  for (int i = ebeg + t; i < eend; i += 256) {
    uint2 p = ebuf[i];
    int off = p.y - node0;
    int r = atomicAdd(&lfill[off], 1);
    col[ebeg + lrp[off] + r] = (int)p.x;
  }
}

// ---------------- weight prep: Wt[n][k] = fp16(W[k][n] * scale) ----------------

template <int COUT>
__global__ __launch_bounds__(256) void k_prep_w(const float* __restrict__ W,
                                                __half* __restrict__ Wt, float scale) {
  int t = blockIdx.x * 256 + threadIdx.x;
  if (t < 128 * COUT) {
    int k = t / COUT, n = t % COUT;
    Wt[n * 128 + k] = __float2half(W[t] * scale);
  }
}

// ---------------- MFMA GEMM (no LDS; fragments straight from L1/L2-hot global) ----

template <int COUT, bool BNRELU, bool XHALF>
__global__ __launch_bounds__(256) void k_gemm_mfma(const void* __restrict__ Xv,
                                                   const __half* __restrict__ Wt,
                                                   const float* __restrict__ dis,
                                                   const float* __restrict__ ss,
                                                   float invs,
                                                   __half* __restrict__ T, int nrows) {
  const int tid = threadIdx.x;
  const int wave = tid >> 6, lane = tid & 63;
  const int rr = lane & 15, kg = lane >> 4;
  const int arow = blockIdx.x * 64 + wave * 16 + rr;
  const int arowc = min(arow, nrows - 1);   // clamp: OOB lanes read valid memory, never store

  constexpr int NT = COUT / 16;
  v4f acc[NT] = {};

#pragma unroll
  for (int kb = 0; kb < 4; ++kb) {
    const int k0 = kb * 32 + kg * 8;
    v8h a;
    if constexpr (XHALF) {
      const __half* X = (const __half*)Xv;
      a = *reinterpret_cast<const v8h*>(X + (size_t)arowc * NCH + k0);
      if constexpr (BNRELU) {
        float4 s0 = *reinterpret_cast<const float4*>(ss + k0);
        float4 s1 = *reinterpret_cast<const float4*>(ss + k0 + 4);
        float4 h0 = *reinterpret_cast<const float4*>(ss + 128 + k0);
        float4 h1 = *reinterpret_cast<const float4*>(ss + 128 + k0 + 4);
        v8h t;
        t[0] = (_Float16)fmaxf(fmaf((float)a[0], s0.x, h0.x), 0.f);
        t[1] = (_Float16)fmaxf(fmaf((float)a[1], s0.y, h0.y), 0.f);
        t[2] = (_Float16)fmaxf(fmaf((float)a[2], s0.z, h0.z), 0.f);
        t[3] = (_Float16)fmaxf(fmaf((float)a[3], s0.w, h0.w), 0.f);
        t[4] = (_Float16)fmaxf(fmaf((float)a[4], s1.x, h1.x), 0.f);
        t[5] = (_Float16)fmaxf(fmaf((float)a[5], s1.y, h1.y), 0.f);
        t[6] = (_Float16)fmaxf(fmaf((float)a[6], s1.z, h1.z), 0.f);
        t[7] = (_Float16)fmaxf(fmaf((float)a[7], s1.w, h1.w), 0.f);
        a = t;
      }
    } else {
      const float* X = (const float*)Xv;
      float4 f0 = *reinterpret_cast<const float4*>(X + (size_t)arowc * NCH + k0);
      float4 f1 = *reinterpret_cast<const float4*>(X + (size_t)arowc * NCH + k0 + 4);
      a[0] = (_Float16)f0.x; a[1] = (_Float16)f0.y;
      a[2] = (_Float16)f0.z; a[3] = (_Float16)f0.w;
      a[4] = (_Float16)f1.x; a[5] = (_Float16)f1.y;
      a[6] = (_Float16)f1.z; a[7] = (_Float16)f1.w;
    }
#pragma unroll
    for (int nt = 0; nt < NT; ++nt) {
      v8h b = *reinterpret_cast<const v8h*>(Wt + (size_t)(nt * 16 + rr) * 128 + k0);
      acc[nt] = __builtin_amdgcn_mfma_f32_16x16x32_f16(a, b, acc[nt], 0, 0, 0);
    }
  }

  const int crow0 = blockIdx.x * 64 + wave * 16 + kg * 4;
#pragma unroll
  for (int reg = 0; reg < 4; ++reg) {
    int r = crow0 + reg;
    if (r < nrows) {
      float dsc = dis[r] * invs;
#pragma unroll
      for (int nt = 0; nt < NT; ++nt)
        T[(size_t)r * COUT + nt * 16 + rr] = __float2half(acc[nt][reg] * dsc);
    }
  }
}

// ---------------- pull aggregation (fp16 gather, f32 accumulate) ----------------
// wave per node; 4 subgroups of 16 lanes, each reading a FULL row per edge
// (16 lanes x 16B = 256B) -> 8 independent row-gathers in flight per wave step.
// Every __shfl at FULL-WAVE scope (shfl inside a divergent branch reads garbage
// when the source lane is exec-masked off — the round-3/4/5 bug).

__device__ __forceinline__ void add8(float* a, uint4 r) {
  const __half2* h = reinterpret_cast<const __half2*>(&r);
#pragma unroll
  for (int i = 0; i < 4; ++i) {
    float2 f = __half22float2(h[i]);
    a[2 * i] += f.x;
    a[2 * i + 1] += f.y;
  }
}

__global__ __launch_bounds__(256) void k_aggregate128(const __half* __restrict__ T,
                                                      const int* __restrict__ rowptr,
                                                      const int* __restrict__ col,
                                                      const float* __restrict__ dis,
                                                      const float* __restrict__ bias,
                                                      __half* __restrict__ OUT, int n) {
  const int lane = threadIdx.x & 63;
  const int node = blockIdx.x * 4 + (threadIdx.x >> 6);
  if (node >= n) return;
  const int sub = lane >> 4;   // 4 concurrent sources
  const int cl = lane & 15;    // channel oct: 8*cl .. 8*cl+7
  const int beg = rowptr[node], end = rowptr[node + 1];

  float acc[8] = {};
  if (sub == 0)
    add8(acc, *reinterpret_cast<const uint4*>(T + (size_t)node * 128 + cl * 8));

  for (int e = beg; e < end;) {
    int cnt = end - e;
    if (cnt > 64) cnt = 64;
    int sl = (e + lane < end) ? col[e + lane] : 0;
    int j = 0;
    for (; j + 8 <= cnt; j += 8) {
      int s0 = __shfl(sl, j + sub);
      int s1 = __shfl(sl, j + 4 + sub);
      uint4 r0 = *reinterpret_cast<const uint4*>(T + (size_t)s0 * 128 + cl * 8);
      uint4 r1 = *reinterpret_cast<const uint4*>(T + (size_t)s1 * 128 + cl * 8);
      add8(acc, r0);
      add8(acc, r1);
    }
    if (j + 4 <= cnt) {
      int s = __shfl(sl, j + sub);          // full-wave shfl
      add8(acc, *reinterpret_cast<const uint4*>(T + (size_t)s * 128 + cl * 8));
      j += 4;
    }
    int rem = cnt - j;                       // 0..3
    if (rem > 0) {
      int s = __shfl(sl, j + (sub < rem ? sub : 0));  // full-wave, valid index
      if (sub < rem)
        add8(acc, *reinterpret_cast<const uint4*>(T + (size_t)s * 128 + cl * 8));
    }
    e += cnt;
  }
  // combine the four subgroups
#pragma unroll
  for (int i = 0; i < 8; ++i) {
    acc[i] += __shfl_xor(acc[i], 16);
    acc[i] += __shfl_xor(acc[i], 32);
  }
  if (sub == 0) {
    float d = dis[node];
    int c = cl * 8;
    __half2 h[4];
#pragma unroll
    for (int i = 0; i < 4; ++i)
      h[i] = __floats2half2_rn(fmaf(acc[2 * i], d, bias[c + 2 * i]),
                               fmaf(acc[2 * i + 1], d, bias[c + 2 * i + 1]));
    *reinterpret_cast<uint4*>(OUT + (size_t)node * 128 + c) =
        *reinterpret_cast<uint4*>(h);
  }
}

__device__ __forceinline__ void add4(float* a, uint2 r) {
  const __half2* h = reinterpret_cast<const __half2*>(&r);
#pragma unroll
  for (int i = 0; i < 2; ++i) {
    float2 f = __half22float2(h[i]);
    a[2 * i] += f.x;
    a[2 * i + 1] += f.y;
  }
}

__global__ __launch_bounds__(256) void k_aggregate64(const __half* __restrict__ T,
                                                     const int* __restrict__ rowptr,
                                                     const int* __restrict__ col,
                                                     const float* __restrict__ dis,
                                                     const float* __restrict__ bias,
                                                     float* __restrict__ OUT, int n) {
  const int lane = threadIdx.x & 63;
  const int node = blockIdx.x * 4 + (threadIdx.x >> 6);
  if (node >= n) return;
  const int sub = lane >> 4;   // 4 concurrent sources
  const int cl = lane & 15;    // channel quad: 4*cl .. 4*cl+3
  const int beg = rowptr[node], end = rowptr[node + 1];

  float acc[4] = {};
  if (sub == 0)
    add4(acc, *reinterpret_cast<const uint2*>(T + (size_t)node * 64 + cl * 4));

  for (int e = beg; e < end;) {
    int cnt = end - e;
    if (cnt > 64) cnt = 64;
    int sl = (e + lane < end) ? col[e + lane] : 0;
    int j = 0;
    for (; j + 8 <= cnt; j += 8) {
      int s0 = __shfl(sl, j + sub);
      int s1 = __shfl(sl, j + 4 + sub);
      uint2 r0 = *reinterpret_cast<const uint2*>(T + (size_t)s0 * 64 + cl * 4);
      uint2 r1 = *reinterpret_cast<const uint2*>(T + (size_t)s1 * 64 + cl * 4);
      add4(acc, r0);
      add4(acc, r1);
    }
    if (j + 4 <= cnt) {
      int s = __shfl(sl, j + sub);          // full-wave shfl
      add4(acc, *reinterpret_cast<const uint2*>(T + (size_t)s * 64 + cl * 4));
      j += 4;
    }
    int rem = cnt - j;                       // 0..3
    if (rem > 0) {
      int s = __shfl(sl, j + (sub < rem ? sub : 0));  // full-wave, valid index
      if (sub < rem)
        add4(acc, *reinterpret_cast<const uint2*>(T + (size_t)s * 64 + cl * 4));
    }
    e += cnt;
  }
#pragma unroll
  for (int i = 0; i < 4; ++i) {
    acc[i] += __shfl_xor(acc[i], 16);
    acc[i] += __shfl_xor(acc[i], 32);
  }
  if (sub == 0) {
    float d = dis[node];
    int c = cl * 4;
    float4 o;
    o.x = fmaf(acc[0], d, bias[c]);
    o.y = fmaf(acc[1], d, bias[c + 1]);
    o.z = fmaf(acc[2], d, bias[c + 2]);
    o.w = fmaf(acc[3], d, bias[c + 3]);
    *reinterpret_cast<float4*>(OUT + (size_t)node * 64 + c) = o;
  }
}

// ---------------- BatchNorm (training-mode batch stats): partial + final ----------------

__global__ __launch_bounds__(256) void k_bn_partial(const __half* __restrict__ H,
                                                    float* __restrict__ part, int nrows) {
  const int lane = threadIdx.x & 63;   // channel pair 2*lane
  const int grp = threadIdx.x >> 6;    // 4 rows in parallel
  const __half2* H2 = reinterpret_cast<const __half2*>(H);
  float2 s = make_float2(0.f, 0.f), s2 = make_float2(0.f, 0.f);
  for (int r = blockIdx.x * 4 + grp; r < nrows; r += gridDim.x * 4) {
    float2 v = __half22float2(H2[(size_t)r * 64 + lane]);
    s.x += v.x; s.y += v.y;
    s2.x += v.x * v.x; s2.y += v.y * v.y;
  }
  __shared__ float2 ls[4][64], ls2[4][64];
  ls[grp][lane] = s;
  ls2[grp][lane] = s2;
  __syncthreads();
  if (grp == 0) {
#pragma unroll
    for (int i = 1; i < 4; ++i) {
      s.x += ls[i][lane].x; s.y += ls[i][lane].y;
      s2.x += ls2[i][lane].x; s2.y += ls2[i][lane].y;
    }
    float* po = part + (size_t)blockIdx.x * 256;
    po[2 * lane] = s.x;
    po[2 * lane + 1] = s.y;
    po[128 + 2 * lane] = s2.x;
    po[128 + 2 * lane + 1] = s2.y;
  }
}

__global__ __launch_bounds__(1024) void k_bn_final(const float* __restrict__ part,
                                                   const float* __restrict__ g,
                                                   const float* __restrict__ bt,
                                                   float* __restrict__ ss, int G, int nrows) {
  const int c = threadIdx.x & 127;
  const int grp = threadIdx.x >> 7;  // 0..7
  float S = 0.f, S2 = 0.f;
  for (int b = grp; b < G; b += 8) {
    S += part[(size_t)b * 256 + c];
    S2 += part[(size_t)b * 256 + 128 + c];
  }
  __shared__ float sS[8][128], sS2[8][128];
  sS[grp][c] = S;
  sS2[grp][c] = S2;
  __syncthreads();
  if (grp == 0) {
#pragma unroll
    for (int i = 1; i < 8; ++i) { S += sS[i][c]; S2 += sS2[i][c]; }
    float inv_n = 1.f / (float)nrows;
    float mean = S * inv_n;
    float var = S2 * inv_n - mean * mean;
    float sc = g[c] * rsqrtf(var + 1e-5f);
    ss[c] = sc;
    ss[128 + c] = bt[c] - mean * sc;
  }
}

// ---------------- driver ----------------

extern "C" void kernel_launch(void* const* d_in, const int* in_sizes, int n_in,
                              void* d_out, int out_size, void* d_ws, size_t ws_size,
                              hipStream_t stream) {
  const float* x  = (const float*)d_in[0];
  const int* ei   = (const int*)d_in[1];
  const float* W1 = (const float*)d_in[2];
  const float* b1 = (const float*)d_in[3];
  const float* g1 = (const float*)d_in[4];
  const float* bt1= (const float*)d_in[5];
  const float* W2 = (const float*)d_in[6];
  const float* b2 = (const float*)d_in[7];
  const float* g2 = (const float*)d_in[8];
  const float* bt2= (const float*)d_in[9];
  const float* W3 = (const float*)d_in[10];
  const float* b3 = (const float*)d_in[11];

  const int N = in_sizes[0] / NCH;
  const int E = in_sizes[1] / 2;
  const int* src = ei;
  const int* dst = ei + E;

  const int NBK = (N + (1 << BSH) - 1) >> BSH;   // buckets (196 for N=100k)
  const int CNTN = NBK * NBLK;                   // cnt entries (50176)
  const int EPB = (E + NBLK - 1) / NBLK;         // edges per slice block

  char* p = (char*)d_ws;
  auto take = [&](size_t bytes) -> char* {
    char* r = p;
    p += (bytes + 255) & ~(size_t)255;
    return r;
  };
  __half* bufT  = (__half*)take((size_t)N * 128 * 2);
  __half* bufH  = (__half*)take((size_t)N * 128 * 2);
  float* dis    = (float*)take((size_t)N * 4);
  int* rowptr   = (int*)take((size_t)(N + 1) * 4);
  int* col      = (int*)take((size_t)E * 4);
  uint2* ebuf   = (uint2*)take((size_t)E * 8);
  int* cnt      = (int*)take((size_t)CNTN * 4);
  int* gbase    = (int*)take((size_t)CNTN * 4);
  int* rptmp    = (int*)take((size_t)CNTN * 4);
  int* bsum     = (int*)take(1024 * 4);
  int* boff     = (int*)take(1024 * 4);
  float* part   = (float*)take((size_t)512 * 256 * 4);
  float* ss1    = (float*)take(256 * 4);
  float* ss2    = (float*)take(256 * 4);
  __half* Wt1   = (__half*)take((size_t)128 * 128 * 2);
  __half* Wt2   = (__half*)take((size_t)128 * 128 * 2);
  __half* Wt3   = (__half*)take((size_t)64 * 128 * 2);

  const int nb64 = (N + 63) / 64;
  const int nbAgg = (N + 3) / 4;
  const int G = 512;
  const int NSC = (CNTN + 1023) / 1024;
  const size_t ldsB = (size_t)NBK * 4;

  const float S1 = 8.f, S2 = 512.f, S3 = 8.f;  // fp16 anti-subnormal weight scales

  // weight prep (independent of graph build)
  k_prep_w<128><<<64, 256, 0, stream>>>(W1, Wt1, S1);
  k_prep_w<128><<<64, 256, 0, stream>>>(W2, Wt2, S2);
  k_prep_w<64><<<32, 256, 0, stream>>>(W3, Wt3, S3);

  // CSR build via bucketed counting sort (recomputed every call; deterministic)
  k_bcount<<<NBLK, 256, ldsB, stream>>>(dst, cnt, E, EPB, NBK);
  k_scan_blockg<<<NSC, 1024, 0, stream>>>(cnt, rptmp, bsum, CNTN);
  k_scan_total<<<1, 1024, 0, stream>>>(bsum, boff, NSC);
  k_scan_fing<<<(CNTN + 255) / 256, 256, 0, stream>>>(rptmp, boff, gbase, CNTN);
  k_bscatter<<<NBLK, 256, ldsB, stream>>>(src, dst, gbase, ebuf, E, EPB, NBK);
  k_bcsr<<<NBK, 256, 0, stream>>>(ebuf, gbase, rowptr, dis, col, N, E, NBK);

  dim3 blk(256);

  // layer 1
  k_gemm_mfma<128, false, false><<<nb64, blk, 0, stream>>>(x, Wt1, dis, nullptr, 1.f / S1, bufT, N);
  k_aggregate128<<<nbAgg, blk, 0, stream>>>(bufT, rowptr, col, dis, b1, bufH, N);
  k_bn_partial<<<G, blk, 0, stream>>>(bufH, part, N);
  k_bn_final<<<1, 1024, 0, stream>>>(part, g1, bt1, ss1, G, N);

  // layer 2 (BN1+ReLU fused into GEMM A-fragment load)
  k_gemm_mfma<128, true, true><<<nb64, blk, 0, stream>>>(bufH, Wt2, dis, ss1, 1.f / S2, bufT, N);
  k_aggregate128<<<nbAgg, blk, 0, stream>>>(bufT, rowptr, col, dis, b2, bufH, N);
  k_bn_partial<<<G, blk, 0, stream>>>(bufH, part, N);
  k_bn_final<<<1, 1024, 0, stream>>>(part, g2, bt2, ss2, G, N);

  // layer 3 (BN2+ReLU fused; aggregate straight into d_out, f32)
  k_gemm_mfma<64, true, true><<<nb64, blk, 0, stream>>>(bufH, Wt3, dis, ss2, 1.f / S3, bufT, N);
  k_aggregate64<<<nbAgg, blk, 0, stream>>>(bufT, rowptr, col, dis, b3, (float*)d_out, N);
}

// Round 11
// 393.264 us; speedup vs baseline: 2.7078x; 1.0178x over previous
//
#include <hip/hip_runtime.h>
#include <hip/hip_fp16.h>

#define NCH 128
#define BSH 9                 // bucket shift: 512 nodes per bucket
#define NBLK 256              // edge-slice blocks for bucket count/scatter

using v8h = __attribute__((ext_vector_type(8))) _Float16;
using v4f = __attribute__((ext_vector_type(4))) float;

// ---------------- bucketed counting-sort CSR build ----------------
// ebuf entries are packed u32: (src << 9) | (dst & 511). src < 2^17, ok.

__global__ __launch_bounds__(256) void k_bcount(const int* __restrict__ dst,
                                                int* __restrict__ cnt,
                                                int E, int epb, int nbk) {
  extern __shared__ int lc[];   // nbk
  for (int i = threadIdx.x; i < nbk; i += 256) lc[i] = 0;
  __syncthreads();
  const int b = blockIdx.x;
  const int e0 = b * epb, e1 = min(E, e0 + epb);
  for (int e = e0 + threadIdx.x; e < e1; e += 256)
    atomicAdd(&lc[dst[e] >> BSH], 1);
  __syncthreads();
  for (int i = threadIdx.x; i < nbk; i += 256)
    cnt[i * NBLK + b] = lc[i];
}

__global__ __launch_bounds__(1024) void k_scan_blockg(const int* __restrict__ in,
                                                      int* __restrict__ rptmp,
                                                      int* __restrict__ bsum, int n) {
  __shared__ int s[1024];
  int tid = threadIdx.x;
  int gid = blockIdx.x * 1024 + tid;
  int v = (gid < n) ? in[gid] : 0;
  s[tid] = v;
  __syncthreads();
  for (int off = 1; off < 1024; off <<= 1) {
    int t = (tid >= off) ? s[tid - off] : 0;
    __syncthreads();
    s[tid] += t;
    __syncthreads();
  }
  if (gid < n) rptmp[gid] = s[tid] - v;  // exclusive
  if (tid == 1023) bsum[blockIdx.x] = s[1023];
}

__global__ __launch_bounds__(1024) void k_scan_total(const int* __restrict__ bsum,
                                                     int* __restrict__ boff, int nb) {
  __shared__ int s[1024];
  int t = threadIdx.x;
  int v = (t < nb) ? bsum[t] : 0;
  s[t] = v;
  __syncthreads();
  for (int off = 1; off < 1024; off <<= 1) {
    int u = (t >= off) ? s[t - off] : 0;
    __syncthreads();
    s[t] += u;
    __syncthreads();
  }
  if (t < nb) boff[t] = s[t] - v;  // exclusive
}

// scatter edges into bucket-sorted packed ebuf; per-(bucket,block) base
// computed inline from rptmp+boff (k_scan_fing folded away).
__global__ __launch_bounds__(256) void k_bscatter(const int* __restrict__ src,
                                                  const int* __restrict__ dst,
                                                  const int* __restrict__ rptmp,
                                                  const int* __restrict__ boff,
                                                  unsigned* __restrict__ ebuf,
                                                  int E, int epb, int nbk) {
  extern __shared__ int sh[];   // lc[nbk] then lbase[nbk]
  int* lc = sh;
  int* lbase = sh + nbk;
  const int b = blockIdx.x;
  for (int i = threadIdx.x; i < nbk; i += 256) {
    lc[i] = 0;
    int g = i * NBLK + b;
    lbase[i] = rptmp[g] + boff[g >> 10];
  }
  __syncthreads();
  const int e0 = b * epb, e1 = min(E, e0 + epb);
  for (int e = e0 + threadIdx.x; e < e1; e += 256) {
    int d = dst[e];
    int bk = d >> BSH;
    int r = atomicAdd(&lc[bk], 1);
    ebuf[lbase[bk] + r] = ((unsigned)src[e] << BSH) | (unsigned)(d & ((1 << BSH) - 1));
  }
}

// per-bucket CSR finalize: rowptr, dis, col. One block per bucket.
__global__ __launch_bounds__(256) void k_bcsr(const unsigned* __restrict__ ebuf,
                                              const int* __restrict__ rptmp,
                                              const int* __restrict__ boff,
                                              int* __restrict__ rowptr,
                                              float* __restrict__ dis,
                                              int* __restrict__ col,
                                              int N, int E, int nbk) {
  __shared__ int ldeg[512], s[512], lrp[512], lfill[512];
  const int b = blockIdx.x;
  const int t = threadIdx.x;
  const int node0 = b << BSH;
  const int g0 = b * NBLK;
  const int ebeg = rptmp[g0] + boff[g0 >> 10];
  int eend = E;
  if (b < nbk - 1) {
    const int g1 = (b + 1) * NBLK;
    eend = rptmp[g1] + boff[g1 >> 10];
  }

  ldeg[t] = 0; ldeg[t + 256] = 0;
  lfill[t] = 0; lfill[t + 256] = 0;
  __syncthreads();
  for (int i = ebeg + t; i < eend; i += 256)
    atomicAdd(&ldeg[ebuf[i] & 511u], 1);
  __syncthreads();
  int v0 = ldeg[t], v1 = ldeg[t + 256];
  s[t] = v0; s[t + 256] = v1;
  __syncthreads();
  for (int off = 1; off < 512; off <<= 1) {
    int a0 = (t >= off) ? s[t - off] : 0;
    int a1 = (t + 256 >= off) ? s[t + 256 - off] : 0;
    __syncthreads();
    s[t] += a0; s[t + 256] += a1;
    __syncthreads();
  }
  lrp[t] = s[t] - v0;              // exclusive
  lrp[t + 256] = s[t + 256] - v1;
  __syncthreads();
#pragma unroll
  for (int q = 0; q < 2; ++q) {
    int i = t + q * 256;
    int node = node0 + i;
    if (node < N) {
      rowptr[node] = ebeg + lrp[i];
      dis[node] = rsqrtf((float)(ldeg[i] + 1));
    }
  }
  if (b == nbk - 1 && t == 0) rowptr[N] = E;
  for (int i = ebeg + t; i < eend; i += 256) {
    unsigned pk = ebuf[i];
    int off = (int)(pk & 511u);
    int r = atomicAdd(&lfill[off], 1);
    col[ebeg + lrp[off] + r] = (int)(pk >> BSH);
  }
}

// ---------------- weight prep (all 3 layers in one launch) ----------------
// Wt[n][k] = fp16(W[k][n] * scale); scale keeps W2 (~5e-4 sigma) out of the
// fp16-subnormal range; 1/scale folded into the GEMM epilogue.

__global__ __launch_bounds__(256) void k_prep_w(const float* __restrict__ W1,
                                                const float* __restrict__ W2,
                                                const float* __restrict__ W3,
                                                __half* __restrict__ Wt1,
                                                __half* __restrict__ Wt2,
                                                __half* __restrict__ Wt3,
                                                float s1, float s2, float s3) {
  int b = blockIdx.x;
  const float* W;
  __half* Wt;
  int cout;
  float sc;
  int t;
  if (b < 64)       { W = W1; Wt = Wt1; cout = 128; sc = s1; t = b * 256 + threadIdx.x; }
  else if (b < 128) { W = W2; Wt = Wt2; cout = 128; sc = s2; t = (b - 64) * 256 + threadIdx.x; }
  else              { W = W3; Wt = Wt3; cout = 64;  sc = s3; t = (b - 128) * 256 + threadIdx.x; }
  if (t < 128 * cout) {
    int k = t / cout, n = t % cout;
    Wt[n * 128 + k] = __float2half(W[t] * sc);
  }
}

// ---------------- MFMA GEMM (no LDS; fragments straight from L1/L2-hot global) ----

template <int COUT, bool BNRELU, bool XHALF>
__global__ __launch_bounds__(256) void k_gemm_mfma(const void* __restrict__ Xv,
                                                   const __half* __restrict__ Wt,
                                                   const float* __restrict__ dis,
                                                   const float* __restrict__ ss,
                                                   float invs,
                                                   __half* __restrict__ T, int nrows) {
  const int tid = threadIdx.x;
  const int wave = tid >> 6, lane = tid & 63;
  const int rr = lane & 15, kg = lane >> 4;
  const int arow = blockIdx.x * 64 + wave * 16 + rr;
  const int arowc = min(arow, nrows - 1);   // clamp: OOB lanes read valid memory, never store

  constexpr int NT = COUT / 16;
  v4f acc[NT] = {};

#pragma unroll
  for (int kb = 0; kb < 4; ++kb) {
    const int k0 = kb * 32 + kg * 8;
    v8h a;
    if constexpr (XHALF) {
      const __half* X = (const __half*)Xv;
      a = *reinterpret_cast<const v8h*>(X + (size_t)arowc * NCH + k0);
      if constexpr (BNRELU) {
        float4 s0 = *reinterpret_cast<const float4*>(ss + k0);
        float4 s1 = *reinterpret_cast<const float4*>(ss + k0 + 4);
        float4 h0 = *reinterpret_cast<const float4*>(ss + 128 + k0);
        float4 h1 = *reinterpret_cast<const float4*>(ss + 128 + k0 + 4);
        v8h t;
        t[0] = (_Float16)fmaxf(fmaf((float)a[0], s0.x, h0.x), 0.f);
        t[1] = (_Float16)fmaxf(fmaf((float)a[1], s0.y, h0.y), 0.f);
        t[2] = (_Float16)fmaxf(fmaf((float)a[2], s0.z, h0.z), 0.f);
        t[3] = (_Float16)fmaxf(fmaf((float)a[3], s0.w, h0.w), 0.f);
        t[4] = (_Float16)fmaxf(fmaf((float)a[4], s1.x, h1.x), 0.f);
        t[5] = (_Float16)fmaxf(fmaf((float)a[5], s1.y, h1.y), 0.f);
        t[6] = (_Float16)fmaxf(fmaf((float)a[6], s1.z, h1.z), 0.f);
        t[7] = (_Float16)fmaxf(fmaf((float)a[7], s1.w, h1.w), 0.f);
        a = t;
      }
    } else {
      const float* X = (const float*)Xv;
      float4 f0 = *reinterpret_cast<const float4*>(X + (size_t)arowc * NCH + k0);
      float4 f1 = *reinterpret_cast<const float4*>(X + (size_t)arowc * NCH + k0 + 4);
      a[0] = (_Float16)f0.x; a[1] = (_Float16)f0.y;
      a[2] = (_Float16)f0.z; a[3] = (_Float16)f0.w;
      a[4] = (_Float16)f1.x; a[5] = (_Float16)f1.y;
      a[6] = (_Float16)f1.z; a[7] = (_Float16)f1.w;
    }
#pragma unroll
    for (int nt = 0; nt < NT; ++nt) {
      v8h b = *reinterpret_cast<const v8h*>(Wt + (size_t)(nt * 16 + rr) * 128 + k0);
      acc[nt] = __builtin_amdgcn_mfma_f32_16x16x32_f16(a, b, acc[nt], 0, 0, 0);
    }
  }

  const int crow0 = blockIdx.x * 64 + wave * 16 + kg * 4;
#pragma unroll
  for (int reg = 0; reg < 4; ++reg) {
    int r = crow0 + reg;
    if (r < nrows) {
      float dsc = dis[r] * invs;
#pragma unroll
      for (int nt = 0; nt < NT; ++nt)
        T[(size_t)r * COUT + nt * 16 + rr] = __float2half(acc[nt][reg] * dsc);
    }
  }
}

// ---------------- pull aggregation (fp16 gather, f32 accumulate) ----------------
// wave per node; 4 subgroups of 16 lanes, each reading a FULL row per edge
// (16 lanes x 16B = 256B) -> 8 independent row-gathers in flight per wave step.
// At the measured random-gather fill ceiling (~3.6 TB/s; round-10 A/B).
// Every __shfl at FULL-WAVE scope (shfl inside a divergent branch reads garbage
// when the source lane is exec-masked off — the round-3/4/5 bug).

__device__ __forceinline__ void add8(float* a, uint4 r) {
  const __half2* h = reinterpret_cast<const __half2*>(&r);
#pragma unroll
  for (int i = 0; i < 4; ++i) {
    float2 f = __half22float2(h[i]);
    a[2 * i] += f.x;
    a[2 * i + 1] += f.y;
  }
}

__global__ __launch_bounds__(256) void k_aggregate128(const __half* __restrict__ T,
                                                      const int* __restrict__ rowptr,
                                                      const int* __restrict__ col,
                                                      const float* __restrict__ dis,
                                                      const float* __restrict__ bias,
                                                      __half* __restrict__ OUT, int n) {
  const int lane = threadIdx.x & 63;
  const int node = blockIdx.x * 4 + (threadIdx.x >> 6);
  if (node >= n) return;
  const int sub = lane >> 4;   // 4 concurrent sources
  const int cl = lane & 15;    // channel oct: 8*cl .. 8*cl+7
  const int beg = rowptr[node], end = rowptr[node + 1];

  float acc[8] = {};
  if (sub == 0)
    add8(acc, *reinterpret_cast<const uint4*>(T + (size_t)node * 128 + cl * 8));

  for (int e = beg; e < end;) {
    int cnt = end - e;
    if (cnt > 64) cnt = 64;
    int sl = (e + lane < end) ? col[e + lane] : 0;
    int j = 0;
    for (; j + 8 <= cnt; j += 8) {
      int s0 = __shfl(sl, j + sub);
      int s1 = __shfl(sl, j + 4 + sub);
      uint4 r0 = *reinterpret_cast<const uint4*>(T + (size_t)s0 * 128 + cl * 8);
      uint4 r1 = *reinterpret_cast<const uint4*>(T + (size_t)s1 * 128 + cl * 8);
      add8(acc, r0);
      add8(acc, r1);
    }
    if (j + 4 <= cnt) {
      int s = __shfl(sl, j + sub);          // full-wave shfl
      add8(acc, *reinterpret_cast<const uint4*>(T + (size_t)s * 128 + cl * 8));
      j += 4;
    }
    int rem = cnt - j;                       // 0..3
    if (rem > 0) {
      int s = __shfl(sl, j + (sub < rem ? sub : 0));  // full-wave, valid index
      if (sub < rem)
        add8(acc, *reinterpret_cast<const uint4*>(T + (size_t)s * 128 + cl * 8));
    }
    e += cnt;
  }
  // combine the four subgroups
#pragma unroll
  for (int i = 0; i < 8; ++i) {
    acc[i] += __shfl_xor(acc[i], 16);
    acc[i] += __shfl_xor(acc[i], 32);
  }
  if (sub == 0) {
    float d = dis[node];
    int c = cl * 8;
    __half2 h[4];
#pragma unroll
    for (int i = 0; i < 4; ++i)
      h[i] = __floats2half2_rn(fmaf(acc[2 * i], d, bias[c + 2 * i]),
                               fmaf(acc[2 * i + 1], d, bias[c + 2 * i + 1]));
    *reinterpret_cast<uint4*>(OUT + (size_t)node * 128 + c) =
        *reinterpret_cast<uint4*>(h);
  }
}

__device__ __forceinline__ void add4(float* a, uint2 r) {
  const __half2* h = reinterpret_cast<const __half2*>(&r);
#pragma unroll
  for (int i = 0; i < 2; ++i) {
    float2 f = __half22float2(h[i]);
    a[2 * i] += f.x;
    a[2 * i + 1] += f.y;
  }
}

__global__ __launch_bounds__(256) void k_aggregate64(const __half* __restrict__ T,
                                                     const int* __restrict__ rowptr,
                                                     const int* __restrict__ col,
                                                     const float* __restrict__ dis,
                                                     const float* __restrict__ bias,
                                                     float* __restrict__ OUT, int n) {
  const int lane = threadIdx.x & 63;
  const int node = blockIdx.x * 4 + (threadIdx.x >> 6);
  if (node >= n) return;
  const int sub = lane >> 4;   // 4 concurrent sources
  const int cl = lane & 15;    // channel quad: 4*cl .. 4*cl+3
  const int beg = rowptr[node], end = rowptr[node + 1];

  float acc[4] = {};
  if (sub == 0)
    add4(acc, *reinterpret_cast<const uint2*>(T + (size_t)node * 64 + cl * 4));

  for (int e = beg; e < end;) {
    int cnt = end - e;
    if (cnt > 64) cnt = 64;
    int sl = (e + lane < end) ? col[e + lane] : 0;
    int j = 0;
    for (; j + 8 <= cnt; j += 8) {
      int s0 = __shfl(sl, j + sub);
      int s1 = __shfl(sl, j + 4 + sub);
      uint2 r0 = *reinterpret_cast<const uint2*>(T + (size_t)s0 * 64 + cl * 4);
      uint2 r1 = *reinterpret_cast<const uint2*>(T + (size_t)s1 * 64 + cl * 4);
      add4(acc, r0);
      add4(acc, r1);
    }
    if (j + 4 <= cnt) {
      int s = __shfl(sl, j + sub);          // full-wave shfl
      add4(acc, *reinterpret_cast<const uint2*>(T + (size_t)s * 64 + cl * 4));
      j += 4;
    }
    int rem = cnt - j;                       // 0..3
    if (rem > 0) {
      int s = __shfl(sl, j + (sub < rem ? sub : 0));  // full-wave, valid index
      if (sub < rem)
        add4(acc, *reinterpret_cast<const uint2*>(T + (size_t)s * 64 + cl * 4));
    }
    e += cnt;
  }
#pragma unroll
  for (int i = 0; i < 4; ++i) {
    acc[i] += __shfl_xor(acc[i], 16);
    acc[i] += __shfl_xor(acc[i], 32);
  }
  if (sub == 0) {
    float d = dis[node];
    int c = cl * 4;
    float4 o;
    o.x = fmaf(acc[0], d, bias[c]);
    o.y = fmaf(acc[1], d, bias[c + 1]);
    o.z = fmaf(acc[2], d, bias[c + 2]);
    o.w = fmaf(acc[3], d, bias[c + 3]);
    *reinterpret_cast<float4*>(OUT + (size_t)node * 64 + c) = o;
  }
}

// ---------------- BatchNorm (training-mode batch stats): partial + final ----------------

__global__ __launch_bounds__(256) void k_bn_partial(const __half* __restrict__ H,
                                                    float* __restrict__ part, int nrows) {
  const int lane = threadIdx.x & 63;   // channel pair 2*lane
  const int grp = threadIdx.x >> 6;    // 4 rows in parallel
  const __half2* H2 = reinterpret_cast<const __half2*>(H);
  float2 s = make_float2(0.f, 0.f), s2 = make_float2(0.f, 0.f);
  for (int r = blockIdx.x * 4 + grp; r < nrows; r += gridDim.x * 4) {
    float2 v = __half22float2(H2[(size_t)r * 64 + lane]);
    s.x += v.x; s.y += v.y;
    s2.x += v.x * v.x; s2.y += v.y * v.y;
  }
  __shared__ float2 ls[4][64], ls2[4][64];
  ls[grp][lane] = s;
  ls2[grp][lane] = s2;
  __syncthreads();
  if (grp == 0) {
#pragma unroll
    for (int i = 1; i < 4; ++i) {
      s.x += ls[i][lane].x; s.y += ls[i][lane].y;
      s2.x += ls2[i][lane].x; s2.y += ls2[i][lane].y;
    }
    float* po = part + (size_t)blockIdx.x * 256;
    po[2 * lane] = s.x;
    po[2 * lane + 1] = s.y;
    po[128 + 2 * lane] = s2.x;
    po[128 + 2 * lane + 1] = s2.y;
  }
}

__global__ __launch_bounds__(1024) void k_bn_final(const float* __restrict__ part,
                                                   const float* __restrict__ g,
                                                   const float* __restrict__ bt,
                                                   float* __restrict__ ss, int G, int nrows) {
  const int c = threadIdx.x & 127;
  const int grp = threadIdx.x >> 7;  // 0..7
  float S = 0.f, S2 = 0.f;
  for (int b = grp; b < G; b += 8) {
    S += part[(size_t)b * 256 + c];
    S2 += part[(size_t)b * 256 + 128 + c];
  }
  __shared__ float sS[8][128], sS2[8][128];
  sS[grp][c] = S;
  sS2[grp][c] = S2;
  __syncthreads();
  if (grp == 0) {
#pragma unroll
    for (int i = 1; i < 8; ++i) { S += sS[i][c]; S2 += sS2[i][c]; }
    float inv_n = 1.f / (float)nrows;
    float mean = S * inv_n;
    float var = S2 * inv_n - mean * mean;
    float sc = g[c] * rsqrtf(var + 1e-5f);
    ss[c] = sc;
    ss[128 + c] = bt[c] - mean * sc;
  }
}

// ---------------- driver ----------------

extern "C" void kernel_launch(void* const* d_in, const int* in_sizes, int n_in,
                              void* d_out, int out_size, void* d_ws, size_t ws_size,
                              hipStream_t stream) {
  const float* x  = (const float*)d_in[0];
  const int* ei   = (const int*)d_in[1];
  const float* W1 = (const float*)d_in[2];
  const float* b1 = (const float*)d_in[3];
  const float* g1 = (const float*)d_in[4];
  const float* bt1= (const float*)d_in[5];
  const float* W2 = (const float*)d_in[6];
  const float* b2 = (const float*)d_in[7];
  const float* g2 = (const float*)d_in[8];
  const float* bt2= (const float*)d_in[9];
  const float* W3 = (const float*)d_in[10];
  const float* b3 = (const float*)d_in[11];

  const int N = in_sizes[0] / NCH;
  const int E = in_sizes[1] / 2;
  const int* src = ei;
  const int* dst = ei + E;

  const int NBK = (N + (1 << BSH) - 1) >> BSH;   // buckets (196 for N=100k)
  const int CNTN = NBK * NBLK;                   // cnt entries (50176)
  const int EPB = (E + NBLK - 1) / NBLK;         // edges per slice block

  char* p = (char*)d_ws;
  auto take = [&](size_t bytes) -> char* {
    char* r = p;
    p += (bytes + 255) & ~(size_t)255;
    return r;
  };
  __half* bufT  = (__half*)take((size_t)N * 128 * 2);
  __half* bufH  = (__half*)take((size_t)N * 128 * 2);
  float* dis    = (float*)take((size_t)N * 4);
  int* rowptr   = (int*)take((size_t)(N + 1) * 4);
  int* col      = (int*)take((size_t)E * 4);
  unsigned* ebuf= (unsigned*)take((size_t)E * 4);
  int* cnt      = (int*)take((size_t)CNTN * 4);
  int* rptmp    = (int*)take((size_t)CNTN * 4);
  int* bsum     = (int*)take(1024 * 4);
  int* boff     = (int*)take(1024 * 4);
  float* part   = (float*)take((size_t)512 * 256 * 4);
  float* ss1    = (float*)take(256 * 4);
  float* ss2    = (float*)take(256 * 4);
  __half* Wt1   = (__half*)take((size_t)128 * 128 * 2);
  __half* Wt2   = (__half*)take((size_t)128 * 128 * 2);
  __half* Wt3   = (__half*)take((size_t)64 * 128 * 2);

  const int nb64 = (N + 63) / 64;
  const int nbAgg = (N + 3) / 4;
  const int G = 512;
  const int NSC = (CNTN + 1023) / 1024;
  const size_t ldsB1 = (size_t)NBK * 4;        // k_bcount
  const size_t ldsB2 = (size_t)NBK * 8;        // k_bscatter (lc + lbase)

  const float S1 = 8.f, S2 = 512.f, S3 = 8.f;  // fp16 anti-subnormal weight scales

  // weight prep (all three layers, one launch)
  k_prep_w<<<160, 256, 0, stream>>>(W1, W2, W3, Wt1, Wt2, Wt3, S1, S2, S3);

  // CSR build via bucketed counting sort (recomputed every call; deterministic)
  k_bcount<<<NBLK, 256, ldsB1, stream>>>(dst, cnt, E, EPB, NBK);
  k_scan_blockg<<<NSC, 1024, 0, stream>>>(cnt, rptmp, bsum, CNTN);
  k_scan_total<<<1, 1024, 0, stream>>>(bsum, boff, NSC);
  k_bscatter<<<NBLK, 256, ldsB2, stream>>>(src, dst, rptmp, boff, ebuf, E, EPB, NBK);
  k_bcsr<<<NBK, 256, 0, stream>>>(ebuf, rptmp, boff, rowptr, dis, col, N, E, NBK);

  dim3 blk(256);

  // layer 1
  k_gemm_mfma<128, false, false><<<nb64, blk, 0, stream>>>(x, Wt1, dis, nullptr, 1.f / S1, bufT, N);
  k_aggregate128<<<nbAgg, blk, 0, stream>>>(bufT, rowptr, col, dis, b1, bufH, N);
  k_bn_partial<<<G, blk, 0, stream>>>(bufH, part, N);
  k_bn_final<<<1, 1024, 0, stream>>>(part, g1, bt1, ss1, G, N);

  // layer 2 (BN1+ReLU fused into GEMM A-fragment load)
  k_gemm_mfma<128, true, true><<<nb64, blk, 0, stream>>>(bufH, Wt2, dis, ss1, 1.f / S2, bufT, N);
  k_aggregate128<<<nbAgg, blk, 0, stream>>>(bufT, rowptr, col, dis, b2, bufH, N);
  k_bn_partial<<<G, blk, 0, stream>>>(bufH, part, N);
  k_bn_final<<<1, 1024, 0, stream>>>(part, g2, bt2, ss2, G, N);

  // layer 3 (BN2+ReLU fused; aggregate straight into d_out, f32)
  k_gemm_mfma<64, true, true><<<nb64, blk, 0, stream>>>(bufH, Wt3, dis, ss2, 1.f / S3, bufT, N);
  k_aggregate64<<<nbAgg, blk, 0, stream>>>(bufT, rowptr, col, dis, b3, (float*)d_out, N);
}